// Round 1
// baseline (308.732 us; speedup 1.0000x reference)
//
#include <hip/hip_runtime.h>

typedef __bf16 bf16;
typedef bf16 bf16x8 __attribute__((ext_vector_type(8)));
typedef bf16 bf16x4 __attribute__((ext_vector_type(4)));
typedef float f32x4 __attribute__((ext_vector_type(4)));

#define MFMA16(a, b, c) __builtin_amdgcn_mfma_f32_16x16x32_bf16(a, b, c, 0, 0, 0)

static constexpr int Bsz = 2, T = 2048, E = 1024, H = 16, Dh = 64;
static constexpr int LDK = 72;  // BK=64 + 8 bf16 pad -> row stride 144B, 2-way LDS conflict max

// Y[M,N] = X[M,K] @ W[N,K]^T (+ bias). X fp32 or bf16; Y bf16 or fp32.
template <bool XF32, bool OUTF32>
__global__ __launch_bounds__(256) void gemm_bt(const float* __restrict__ Xf,
                                               const bf16* __restrict__ Xb,
                                               const float* __restrict__ W,
                                               bf16* __restrict__ Yb,
                                               float* __restrict__ Yf,
                                               const float* __restrict__ bias,
                                               int K, int N) {
    __shared__ bf16 At[128 * LDK];
    __shared__ bf16 Bt[128 * LDK];
    const int tid = threadIdx.x;
    const int lane = tid & 63;
    const int wave = tid >> 6;
    const int wm = wave >> 1, wn = wave & 1;  // 2x2 waves, 64x64 out each
    const int m0 = blockIdx.x * 128, n0 = blockIdx.y * 128;
    const int fr = lane & 15;         // fragment row (A) / col (B)
    const int kg = (lane >> 4) << 3;  // k offset: 8 contiguous per lane-group

    f32x4 acc[4][4] = {};

    for (int k0 = 0; k0 < K; k0 += 64) {
        // ---- stage A tile (128 x 64) ----
        if constexpr (XF32) {
#pragma unroll
            for (int i = 0; i < 8; ++i) {
                int g = tid + i * 256;  // 2048 float4 groups
                int row = g >> 4, c4 = (g & 15) << 2;
                const float4 v = *(const float4*)(Xf + (size_t)(m0 + row) * K + k0 + c4);
                bf16x4 bv = {(bf16)v.x, (bf16)v.y, (bf16)v.z, (bf16)v.w};
                *(bf16x4*)(At + row * LDK + c4) = bv;
            }
        } else {
#pragma unroll
            for (int i = 0; i < 4; ++i) {
                int g = tid + i * 256;  // 1024 bf16x8 groups
                int row = g >> 3, c8 = (g & 7) << 3;
                bf16x8 v = *(const bf16x8*)(Xb + (size_t)(m0 + row) * K + k0 + c8);
                *(bf16x8*)(At + row * LDK + c8) = v;
            }
        }
        // ---- stage B tile from W[N][K] fp32 ----
#pragma unroll
        for (int i = 0; i < 8; ++i) {
            int g = tid + i * 256;
            int row = g >> 4, c4 = (g & 15) << 2;
            const float4 v = *(const float4*)(W + (size_t)(n0 + row) * K + k0 + c4);
            bf16x4 bv = {(bf16)v.x, (bf16)v.y, (bf16)v.z, (bf16)v.w};
            *(bf16x4*)(Bt + row * LDK + c4) = bv;
        }
        __syncthreads();
#pragma unroll
        for (int kk = 0; kk < 64; kk += 32) {
            bf16x8 af[4], bfr[4];
#pragma unroll
            for (int f = 0; f < 4; ++f)
                af[f] = *(const bf16x8*)(At + (wm * 64 + f * 16 + fr) * LDK + kk + kg);
#pragma unroll
            for (int f = 0; f < 4; ++f)
                bfr[f] = *(const bf16x8*)(Bt + (wn * 64 + f * 16 + fr) * LDK + kk + kg);
#pragma unroll
            for (int mf = 0; mf < 4; ++mf)
#pragma unroll
                for (int nf = 0; nf < 4; ++nf)
                    acc[mf][nf] = MFMA16(af[mf], bfr[nf], acc[mf][nf]);
        }
        __syncthreads();
    }
    // C/D layout: col = lane&15, row = (lane>>4)*4 + reg  [guide m89-verified]
    const int rb = (lane >> 4) << 2;
#pragma unroll
    for (int mf = 0; mf < 4; ++mf)
#pragma unroll
        for (int nf = 0; nf < 4; ++nf) {
            int n = n0 + wn * 64 + nf * 16 + fr;
#pragma unroll
            for (int r = 0; r < 4; ++r) {
                int mm = m0 + wm * 64 + mf * 16 + rb + r;
                float v = acc[mf][nf][r];
                if constexpr (OUTF32)
                    Yf[(size_t)mm * N + n] = v + bias[n];
                else
                    Yb[(size_t)mm * N + n] = (bf16)v;
            }
        }
}

// Flash attention, causal. Grid: (T/64, H, B); 4 waves/block, 16 q-rows/wave.
// Q,K,V,O are [B*T, E] bf16; head h occupies cols h*64..h*64+63.
__global__ __launch_bounds__(256) void attn_fwd(const bf16* __restrict__ Q,
                                                const bf16* __restrict__ K,
                                                const bf16* __restrict__ V,
                                                bf16* __restrict__ O) {
    __shared__ bf16 Vt[4][64 * 40];  // per-wave V^T tile [d=64][key=32], stride 40 (pad)
    __shared__ bf16 Pl[4][16 * 40];  // per-wave P tile [q=16][key=32], stride 40

    const int tid = threadIdx.x, lane = tid & 63, w = tid >> 6;
    const int h = blockIdx.y, b = blockIdx.z;
    const int q0 = blockIdx.x * 64 + w * 16;
    const int fr = lane & 15, grp = lane >> 4, kg = grp << 3;

    const bf16* Qp = Q + (size_t)b * T * E + h * Dh;
    const bf16* Kp = K + (size_t)b * T * E + h * Dh;
    const bf16* Vp = V + (size_t)b * T * E + h * Dh;

    // Q fragments hoisted: A-layout row = lane&15, k = (lane>>4)*8+j (+32)
    bf16x8 qf0 = *(const bf16x8*)(Qp + (size_t)(q0 + fr) * E + kg);
    bf16x8 qf1 = *(const bf16x8*)(Qp + (size_t)(q0 + fr) * E + 32 + kg);

    float m[4], l[4] = {0.f, 0.f, 0.f, 0.f};
#pragma unroll
    for (int r = 0; r < 4; ++r) m[r] = -1e30f;
    f32x4 o[4] = {};

    const int ktmax = (q0 + 15) >> 5;  // inclusive, KV tiles of 32
    for (int kt = 0; kt <= ktmax; ++kt) {
        const int kb = kt * 32;
        // ---- stage V^T tile (coalesced 16B global reads, scalar LDS writes) ----
        {
            int key = lane >> 1;
#pragma unroll
            for (int it = 0; it < 4; ++it) {
                int d0 = ((lane & 1) + it * 2) << 3;
                bf16x8 vv = *(const bf16x8*)(Vp + (size_t)(kb + key) * E + d0);
#pragma unroll
                for (int j = 0; j < 8; ++j) Vt[w][(d0 + j) * 40 + key] = vv[j];
            }
        }
        // ---- QK^T: S[16 q][32 keys] as two 16-col fragments ----
        f32x4 s[2];
#pragma unroll
        for (int c = 0; c < 2; ++c) {
            const bf16* kp = Kp + (size_t)(kb + c * 16 + fr) * E + kg;
            bf16x8 kf0 = *(const bf16x8*)(kp);
            bf16x8 kf1 = *(const bf16x8*)(kp + 32);
            f32x4 z = {};
            z = MFMA16(qf0, kf0, z);
            z = MFMA16(qf1, kf1, z);
            s[c] = z;
        }
        // ---- scale (1/sqrt(64)) + causal mask + tile row-max ----
        float tm[4];
#pragma unroll
        for (int r = 0; r < 4; ++r) {
            int qrow = q0 + (grp << 2) + r;
            float v0 = s[0][r] * 0.125f;
            float v1 = s[1][r] * 0.125f;
            if (kb + fr > qrow) v0 = -1e30f;
            if (kb + 16 + fr > qrow) v1 = -1e30f;
            s[0][r] = v0;
            s[1][r] = v1;
            tm[r] = fmaxf(v0, v1);
        }
#pragma unroll
        for (int off = 8; off >= 1; off >>= 1)
#pragma unroll
            for (int r = 0; r < 4; ++r) tm[r] = fmaxf(tm[r], __shfl_xor(tm[r], off, 64));
        // ---- online softmax update ----
        float ps[4];
#pragma unroll
        for (int r = 0; r < 4; ++r) {
            float mn = fmaxf(m[r], tm[r]);
            float a = __expf(m[r] - mn);
            m[r] = mn;
            float p0 = __expf(s[0][r] - mn);
            float p1 = __expf(s[1][r] - mn);
            s[0][r] = p0;
            s[1][r] = p1;
            l[r] *= a;
            ps[r] = p0 + p1;
            o[0][r] *= a;
            o[1][r] *= a;
            o[2][r] *= a;
            o[3][r] *= a;
        }
#pragma unroll
        for (int off = 8; off >= 1; off >>= 1)
#pragma unroll
            for (int r = 0; r < 4; ++r) ps[r] += __shfl_xor(ps[r], off, 64);
#pragma unroll
        for (int r = 0; r < 4; ++r) l[r] += ps[r];
        // ---- P (C-layout) -> LDS -> A-layout fragment ----
#pragma unroll
        for (int c = 0; c < 2; ++c)
#pragma unroll
            for (int r = 0; r < 4; ++r)
                Pl[w][((grp << 2) + r) * 40 + c * 16 + fr] = (bf16)s[c][r];
        bf16x8 pa = *(const bf16x8*)(&Pl[w][fr * 40 + kg]);
        // ---- PV: O[16][64] += P[16][32] @ V[32][64] ----
#pragma unroll
        for (int dc = 0; dc < 4; ++dc) {
            bf16x8 vf = *(const bf16x8*)(&Vt[w][(dc * 16 + fr) * 40 + kg]);
            o[dc] = MFMA16(pa, vf, o[dc]);
        }
    }
    // ---- epilogue: normalize + store bf16 ----
    bf16* Op = O + (size_t)b * T * E + h * Dh;
#pragma unroll
    for (int r = 0; r < 4; ++r) {
        float inv = 1.0f / l[r];
        int qrow = q0 + (grp << 2) + r;
#pragma unroll
        for (int dc = 0; dc < 4; ++dc)
            Op[(size_t)qrow * E + dc * 16 + fr] = (bf16)(o[dc][r] * inv);
    }
}

extern "C" void kernel_launch(void* const* d_in, const int* in_sizes, int n_in,
                              void* d_out, int out_size, void* d_ws, size_t ws_size,
                              hipStream_t stream) {
    const float* k_in = (const float*)d_in[0];
    const float* q_in = (const float*)d_in[1];
    const float* v_in = (const float*)d_in[2];
    const float* Wk = (const float*)d_in[3];
    const float* Wq = (const float*)d_in[4];
    const float* Wv = (const float*)d_in[5];
    const float* Wo = (const float*)d_in[6];
    const float* bo = (const float*)d_in[7];
    float* out = (float*)d_out;

    const size_t NE = (size_t)Bsz * T * E;  // 4,194,304 elems
    bf16* Qb = (bf16*)d_ws;                 // ws usage: 4 * 8 MB = 33.6 MB
    bf16* Kb = Qb + NE;
    bf16* Vb = Kb + NE;
    bf16* Ab = Vb + NE;

    dim3 gg(Bsz * T / 128, E / 128), bb(256);
    // projections (no bias): X fp32 -> bf16 out
    gemm_bt<true, false><<<gg, bb, 0, stream>>>(q_in, nullptr, Wq, Qb, nullptr, nullptr, E, E);
    gemm_bt<true, false><<<gg, bb, 0, stream>>>(k_in, nullptr, Wk, Kb, nullptr, nullptr, E, E);
    gemm_bt<true, false><<<gg, bb, 0, stream>>>(v_in, nullptr, Wv, Vb, nullptr, nullptr, E, E);
    // attention
    attn_fwd<<<dim3(T / 64, H, Bsz), bb, 0, stream>>>(Qb, Kb, Vb, Ab);
    // output projection: bf16 X, fp32 out + bias
    gemm_bt<false, true><<<gg, bb, 0, stream>>>(nullptr, Ab, Wo, nullptr, out, bo, E, E);
}

// Round 2
// 202.247 us; speedup vs baseline: 1.5265x; 1.5265x over previous
//
#include <hip/hip_runtime.h>
#include <stdint.h>

typedef __bf16 bf16;
typedef bf16 bf16x8 __attribute__((ext_vector_type(8)));
typedef bf16 bf16x4 __attribute__((ext_vector_type(4)));
typedef float f32x4 __attribute__((ext_vector_type(4)));
typedef float f32x16 __attribute__((ext_vector_type(16)));
typedef unsigned int uint;
typedef uint u32x4 __attribute__((ext_vector_type(4)));

#define MFMA16(a, b, c) __builtin_amdgcn_mfma_f32_16x16x32_bf16(a, b, c, 0, 0, 0)
#define MFMA32(a, b, c) __builtin_amdgcn_mfma_f32_32x32x16_bf16(a, b, c, 0, 0, 0)

static constexpr int Bsz = 2, T = 2048, E = 1024, H = 16, Dh = 64;
static constexpr int LDK = 72;  // 64 + 8 bf16 pad

// ---------------- GEMM: Y[M,N] = X[M,K] @ W[N,K]^T (+bias) -----------------
template <bool XF32, bool OUTF32, int BN>
__device__ __forceinline__ void gemm_body(bf16* At, bf16* Bt,
                                          const float* __restrict__ Xf,
                                          const bf16* __restrict__ Xb,
                                          const float* __restrict__ W,
                                          bf16* __restrict__ Yb,
                                          float* __restrict__ Yf,
                                          const float* __restrict__ bias,
                                          int K, int N) {
    constexpr int NF = BN / 32;  // B-fragments per wave (wave tile 64 x BN/2)
    const int tid = threadIdx.x, lane = tid & 63, wave = tid >> 6;
    const int wm = wave >> 1, wn = wave & 1;
    const int m0 = blockIdx.x * 128, n0 = blockIdx.y * BN;
    const int fr = lane & 15, kg = (lane >> 4) << 3;

    f32x4 acc[4][NF] = {};

    for (int k0 = 0; k0 < K; k0 += 64) {
        if constexpr (XF32) {
#pragma unroll
            for (int i = 0; i < 8; ++i) {
                int g = tid + i * 256;
                int row = g >> 4, c4 = (g & 15) << 2;
                const float4 v = *(const float4*)(Xf + (size_t)(m0 + row) * K + k0 + c4);
                bf16x4 bv = {(bf16)v.x, (bf16)v.y, (bf16)v.z, (bf16)v.w};
                *(bf16x4*)(At + row * LDK + c4) = bv;
            }
        } else {
#pragma unroll
            for (int i = 0; i < 4; ++i) {
                int g = tid + i * 256;
                int row = g >> 3, c8 = (g & 7) << 3;
                bf16x8 v = *(const bf16x8*)(Xb + (size_t)(m0 + row) * K + k0 + c8);
                *(bf16x8*)(At + row * LDK + c8) = v;
            }
        }
#pragma unroll
        for (int i = 0; i < BN / 16; ++i) {
            int g = tid + i * 256;
            int row = g >> 4, c4 = (g & 15) << 2;
            const float4 v = *(const float4*)(W + (size_t)(n0 + row) * K + k0 + c4);
            bf16x4 bv = {(bf16)v.x, (bf16)v.y, (bf16)v.z, (bf16)v.w};
            *(bf16x4*)(Bt + row * LDK + c4) = bv;
        }
        __syncthreads();
#pragma unroll
        for (int kk = 0; kk < 64; kk += 32) {
            bf16x8 af[4], bfr[NF];
#pragma unroll
            for (int f = 0; f < 4; ++f)
                af[f] = *(const bf16x8*)(At + (wm * 64 + f * 16 + fr) * LDK + kk + kg);
#pragma unroll
            for (int f = 0; f < NF; ++f)
                bfr[f] = *(const bf16x8*)(Bt + (wn * (BN / 2) + f * 16 + fr) * LDK + kk + kg);
#pragma unroll
            for (int mf = 0; mf < 4; ++mf)
#pragma unroll
                for (int nf = 0; nf < NF; ++nf)
                    acc[mf][nf] = MFMA16(af[mf], bfr[nf], acc[mf][nf]);
        }
        __syncthreads();
    }
    const int rb = (lane >> 4) << 2;
#pragma unroll
    for (int mf = 0; mf < 4; ++mf)
#pragma unroll
        for (int nf = 0; nf < NF; ++nf) {
            int n = n0 + wn * (BN / 2) + nf * 16 + fr;
#pragma unroll
            for (int r = 0; r < 4; ++r) {
                int mm = m0 + wm * 64 + mf * 16 + rb + r;
                float v = acc[mf][nf][r];
                if constexpr (OUTF32)
                    Yf[(size_t)mm * N + n] = v + bias[n];
                else
                    Yb[(size_t)mm * N + n] = (bf16)v;
            }
        }
}

// Fused projections. z=0: Q=q@Wq^T [4096x1024]; z=1: K=k@Wk^T;
// z=2,3: Vt_b = Wv @ v_b^T  [1024 x 2048] per batch (V pre-transposed!).
__global__ __launch_bounds__(256) void qkv_proj(const float* __restrict__ q,
                                                const float* __restrict__ k,
                                                const float* __restrict__ v,
                                                const float* __restrict__ Wq,
                                                const float* __restrict__ Wk,
                                                const float* __restrict__ Wv,
                                                bf16* __restrict__ Qb, bf16* __restrict__ Kb,
                                                bf16* __restrict__ Vt) {
    __shared__ bf16 At[128 * LDK];
    __shared__ bf16 Bt[128 * LDK];
    const int z = blockIdx.z;
    if (z < 2) {
        if (blockIdx.y >= 8) return;  // N=1024
        gemm_body<true, false, 128>(At, Bt, z ? k : q, nullptr, z ? Wk : Wq,
                                    z ? Kb : Qb, nullptr, nullptr, E, E);
    } else {
        if (blockIdx.x >= 8) return;  // M=1024
        int b = z - 2;
        gemm_body<true, false, 128>(At, Bt, Wv, nullptr, v + (size_t)b * T * E,
                                    Vt + (size_t)b * E * T, nullptr, nullptr, E, T);
    }
}

__global__ __launch_bounds__(256) void out_proj(const bf16* __restrict__ Xb,
                                                const float* __restrict__ W,
                                                float* __restrict__ Y,
                                                const float* __restrict__ bias) {
    __shared__ bf16 At[128 * LDK];
    __shared__ bf16 Bt[64 * LDK];
    gemm_body<false, true, 64>(At, Bt, nullptr, Xb, W, nullptr, Y, bias, E, E);
}

// ---------------- Attention: swapped-QK^T 32x32 structure ------------------
__device__ __forceinline__ uint pkbf(float a, float b) {
    uint16_t x = __builtin_bit_cast(uint16_t, (bf16)a);
    uint16_t y = __builtin_bit_cast(uint16_t, (bf16)b);
    return (uint)x | ((uint)y << 16);
}

// One 32-key x 32-q tile. State: q = lane&31 (replicated across lane halves).
template <bool DIAG>
__device__ __forceinline__ void attn_tile(int kb, int q0, int l31, int hi,
                                          const bf16* __restrict__ Kp,
                                          const bf16* __restrict__ Vp,
                                          const bf16x8 (&qf)[4],
                                          f32x16& o0, f32x16& o1, float& m, float& l) {
    // K A-fragments: row = key = lane&31, k(d) = t*16 + hi*8 + j
    bf16x8 kf[4];
#pragma unroll
    for (int t = 0; t < 4; ++t)
        kf[t] = *(const bf16x8*)(Kp + (size_t)(kb + l31) * E + t * 16 + hi * 8);
    // V^T B-fragments: col = d = db*32 + lane&31, k(key) = c*16 + hi*8 + j
    bf16x8 vf[2][2];
#pragma unroll
    for (int db = 0; db < 2; ++db)
#pragma unroll
        for (int c = 0; c < 2; ++c)
            vf[db][c] = *(const bf16x8*)(Vp + (size_t)(db * 32 + l31) * T + kb + c * 16 + hi * 8);

    // S^T[key][q]: C col = q = lane&31, row = key = (r&3)+8*(r>>2)+4*hi
    f32x16 s = {};
#pragma unroll
    for (int t = 0; t < 4; ++t) s = MFMA32(kf[t], qf[t], s);

    float sv[16];
#pragma unroll
    for (int r = 0; r < 16; ++r) {
        float x = s[r] * 0.125f;  // 1/sqrt(64)
        if constexpr (DIAG) {
            int key = (r & 3) + 8 * (r >> 2) + 4 * hi;
            if (key > l31) x = -1e30f;  // causal: mask key > q
        }
        sv[r] = x;
    }
    // tile row-max: in-register + one cross-half exchange
    float pm = sv[0];
#pragma unroll
    for (int r = 1; r < 16; ++r) pm = fmaxf(pm, sv[r]);
    pm = fmaxf(pm, __shfl_xor(pm, 32, 64));

    // deferred rescale (T13, THR=8)
    if (!__all(pm - m <= 8.0f)) {
        float mn = fmaxf(m, pm);
        float al = __expf(m - mn);
        m = mn;
        l *= al;
#pragma unroll
        for (int r = 0; r < 16; ++r) {
            int qr = (r & 3) + 8 * (r >> 2) + 4 * hi;
            float aq = __shfl(al, qr, 64);
            o0[r] *= aq;
            o1[r] *= aq;
        }
    }
    // P = exp(s - m), row-sum
    float p[16];
    float ps = 0.f;
#pragma unroll
    for (int r = 0; r < 16; ++r) {
        p[r] = __expf(sv[r] - m);
        ps += p[r];
    }
    l += ps + __shfl_xor(ps, 32, 64);

    // P -> PV A-fragments (row=q=lane&31, k=key=cc*16+hi*8+j), in registers
#pragma unroll
    for (int cc = 0; cc < 2; ++cc) {
        int bse = cc * 8;
        uint x0 = pkbf(p[bse + 0], p[bse + 1]);
        uint x1 = pkbf(p[bse + 2], p[bse + 3]);
        uint y0 = pkbf(p[bse + 4], p[bse + 5]);
        uint y1 = pkbf(p[bse + 6], p[bse + 7]);
        uint sx0 = __shfl_xor(x0, 32, 64), sx1 = __shfl_xor(x1, 32, 64);
        uint sy0 = __shfl_xor(y0, 32, 64), sy1 = __shfl_xor(y1, 32, 64);
        u32x4 wv;
        wv.x = hi ? sy0 : x0;
        wv.y = hi ? sy1 : x1;
        wv.z = hi ? y0 : sx0;
        wv.w = hi ? y1 : sx1;
        bf16x8 pa = __builtin_bit_cast(bf16x8, wv);
        o0 = MFMA32(pa, vf[0][cc], o0);
        o1 = MFMA32(pa, vf[1][cc], o1);
    }
}

// 1 wave per block, 32 q-rows per wave. XCD-swizzled: each XCD owns 4 heads.
__global__ __launch_bounds__(64) void attn_fwd(const bf16* __restrict__ Q,
                                               const bf16* __restrict__ K,
                                               const bf16* __restrict__ Vt,
                                               bf16* __restrict__ O) {
    const int g = blockIdx.x;
    const int xcd = g & 7, j = g >> 3;
    const int hb = xcd * 4 + (j >> 6);  // 0..31
    const int qt = 63 - (j & 63);       // heavy q-tiles first
    const int h = hb & 15, b = hb >> 4;

    const int lane = threadIdx.x & 63;
    const int l31 = lane & 31, hi = lane >> 5;
    const int q0 = qt * 32;

    const bf16* Qp = Q + (size_t)b * T * E + h * Dh;
    const bf16* Kp = K + (size_t)b * T * E + h * Dh;
    const bf16* Vp = Vt + ((size_t)b * E + h * Dh) * T;  // [d][t]

    // Q B-fragments hoisted: col = q = lane&31, k(d) = t*16 + hi*8 + j
    bf16x8 qf[4];
#pragma unroll
    for (int t = 0; t < 4; ++t)
        qf[t] = *(const bf16x8*)(Qp + (size_t)(q0 + l31) * E + t * 16 + hi * 8);

    f32x16 o0 = {}, o1 = {};
    float m = -1e30f, l = 0.f;

    for (int kt = 0; kt < qt; ++kt)
        attn_tile<false>(kt * 32, q0, l31, hi, Kp, Vp, qf, o0, o1, m, l);
    attn_tile<true>(qt * 32, q0, l31, hi, Kp, Vp, qf, o0, o1, m, l);

    // epilogue: O[q][d] has q in regs -> fetch l per-row, normalize, store
    bf16* Op = O + (size_t)b * T * E + h * Dh;
#pragma unroll
    for (int r = 0; r < 16; ++r) {
        int qr = (r & 3) + 8 * (r >> 2) + 4 * hi;
        float lq = __shfl(l, qr, 64);
        float inv = 1.0f / lq;
        Op[(size_t)(q0 + qr) * E + l31] = (bf16)(o0[r] * inv);
        Op[(size_t)(q0 + qr) * E + 32 + l31] = (bf16)(o1[r] * inv);
    }
}

extern "C" void kernel_launch(void* const* d_in, const int* in_sizes, int n_in,
                              void* d_out, int out_size, void* d_ws, size_t ws_size,
                              hipStream_t stream) {
    const float* k_in = (const float*)d_in[0];
    const float* q_in = (const float*)d_in[1];
    const float* v_in = (const float*)d_in[2];
    const float* Wk = (const float*)d_in[3];
    const float* Wq = (const float*)d_in[4];
    const float* Wv = (const float*)d_in[5];
    const float* Wo = (const float*)d_in[6];
    const float* bo = (const float*)d_in[7];
    float* out = (float*)d_out;

    const size_t NE = (size_t)Bsz * T * E;
    bf16* Qb = (bf16*)d_ws;   // [B*T][E]
    bf16* Kb = Qb + NE;       // [B*T][E]
    bf16* Vtw = Kb + NE;      // [B][E][T]  (pre-transposed V)
    bf16* Ab = Vtw + NE;      // [B*T][E]

    qkv_proj<<<dim3(32, 16, 4), 256, 0, stream>>>(q_in, k_in, v_in, Wq, Wk, Wv, Qb, Kb, Vtw);
    attn_fwd<<<dim3(64 * H * Bsz, 1, 1), 64, 0, stream>>>(Qb, Kb, Vtw, Ab);
    out_proj<<<dim3(32, 16), 256, 0, stream>>>(Ab, Wo, out, bo);
}

// Round 3
// 180.682 us; speedup vs baseline: 1.7087x; 1.1194x over previous
//
#include <hip/hip_runtime.h>
#include <stdint.h>

typedef __bf16 bf16;
typedef bf16 bf16x8 __attribute__((ext_vector_type(8)));
typedef bf16 bf16x4 __attribute__((ext_vector_type(4)));
typedef float f32x4 __attribute__((ext_vector_type(4)));
typedef float f32x16 __attribute__((ext_vector_type(16)));
typedef unsigned int uint;
typedef uint u32x4 __attribute__((ext_vector_type(4)));

#define MFMA16(a, b, c) __builtin_amdgcn_mfma_f32_16x16x32_bf16(a, b, c, 0, 0, 0)
#define MFMA32(a, b, c) __builtin_amdgcn_mfma_f32_32x32x16_bf16(a, b, c, 0, 0, 0)

static constexpr int Bsz = 2, T = 2048, E = 1024, H = 16, Dh = 64;

// async global->LDS, 16B per lane. LDS dest must be wave-uniform base (HW adds lane*16).
__device__ __forceinline__ void gll16(const bf16* g, bf16* l) {
    __builtin_amdgcn_global_load_lds((const __attribute__((address_space(1))) uint*)g,
                                     (__attribute__((address_space(3))) uint*)l, 16, 0, 0);
}

// ---- staging: ROWS x 64 bf16 tile into linear LDS ([row][64], 128B rows) ----
template <int ROWS>
__device__ __forceinline__ void stage_b16(bf16* lds, const bf16* g, int ldg, int wave, int lane) {
#pragma unroll
    for (int i = 0; i < ROWS / 32; ++i) {
        const int row = wave * (ROWS / 4) + i * 8;  // wave-uniform
        gll16(g + (size_t)(row + (lane >> 3)) * ldg + (lane & 7) * 8, lds + row * 64);
    }
}
template <int ROWS>
__device__ __forceinline__ void stage_f32(bf16* lds, const float* g, int ldg, int tid) {
#pragma unroll
    for (int i = 0; i < ROWS / 16; ++i) {
        int gg = tid + i * 256;
        int row = gg >> 4, c4 = (gg & 15) << 2;
        const float4 v = *(const float4*)(g + (size_t)row * ldg + c4);
        bf16x4 bv = {(bf16)v.x, (bf16)v.y, (bf16)v.z, (bf16)v.w};
        *(bf16x4*)(lds + row * 64 + c4) = bv;
    }
}

// ------------- GEMM body: Y[M,N] = A[M,K] @ B[N,K]^T (+bias) ---------------
template <bool AB16, bool BB16, int MF, int NF, bool OUTF32>
__device__ __forceinline__ void gemm_body(bf16* At, bf16* Bt,
                                          const bf16* A16, const float* A32,
                                          const bf16* B16, const float* B32,
                                          bf16* Yb, float* Yf, const float* bias,
                                          int m0, int n0, int K, int ldy) {
    constexpr int BM = MF * 32, BN = NF * 32;
    const int tid = threadIdx.x, lane = tid & 63, wave = tid >> 6;
    const int wm = wave >> 1, wn = wave & 1;
    const int fr = lane & 15, kg = (lane >> 4) << 3;

    f32x4 acc[MF][NF] = {};

    for (int k0 = 0; k0 < K; k0 += 64) {
        if constexpr (AB16)
            stage_b16<BM>(At, A16 + (size_t)m0 * K + k0, K, wave, lane);
        else
            stage_f32<BM>(At, A32 + (size_t)m0 * K + k0, K, tid);
        if constexpr (BB16)
            stage_b16<BN>(Bt, B16 + (size_t)n0 * K + k0, K, wave, lane);
        else
            stage_f32<BN>(Bt, B32 + (size_t)n0 * K + k0, K, tid);
        __syncthreads();  // compiler drains vmcnt(0) for global_load_lds here
#pragma unroll
        for (int kk = 0; kk < 64; kk += 32) {
            bf16x8 af[MF], bfr[NF];
#pragma unroll
            for (int f = 0; f < MF; ++f)
                af[f] = *(const bf16x8*)(At + (wm * (BM / 2) + f * 16 + fr) * 64 + kk + kg);
#pragma unroll
            for (int f = 0; f < NF; ++f)
                bfr[f] = *(const bf16x8*)(Bt + (wn * (BN / 2) + f * 16 + fr) * 64 + kk + kg);
#pragma unroll
            for (int mf = 0; mf < MF; ++mf)
#pragma unroll
                for (int nf = 0; nf < NF; ++nf)
                    acc[mf][nf] = MFMA16(af[mf], bfr[nf], acc[mf][nf]);
        }
        __syncthreads();
    }
    const int rb = (lane >> 4) << 2;
#pragma unroll
    for (int mf = 0; mf < MF; ++mf)
#pragma unroll
        for (int nf = 0; nf < NF; ++nf) {
            int n = n0 + wn * (BN / 2) + nf * 16 + fr;
            float bn = 0.f;
            if constexpr (OUTF32) bn = bias[n];
#pragma unroll
            for (int r = 0; r < 4; ++r) {
                int mm = m0 + wm * (BM / 2) + mf * 16 + rb + r;
                float v = acc[mf][nf][r];
                if constexpr (OUTF32)
                    Yf[(size_t)mm * ldy + n] = v + bn;
                else
                    Yb[(size_t)mm * ldy + n] = (bf16)v;
            }
        }
}

// fp32 -> bf16 conversion pass (x inputs optional). 16M elems max, 4/thread.
__global__ __launch_bounds__(256) void cvt_all(const float* q, const float* k, const float* v,
                                               const float* Wq, const float* Wk,
                                               const float* Wv, const float* Wo,
                                               bf16* qc, bf16* kc, bf16* vc,
                                               bf16* Wqc, bf16* Wkc, bf16* Wvc, bf16* Woc,
                                               int doX) {
    const size_t NX = (size_t)Bsz * T * E;  // 4M
    const size_t NW = (size_t)E * E;        // 1M
    const size_t xtot = doX ? 3 * NX : 0;
    const size_t nwork = (xtot + 4 * NW) >> 2;
    for (size_t t = (size_t)blockIdx.x * 256 + threadIdx.x; t < nwork;
         t += (size_t)gridDim.x * 256) {
        size_t i = t << 2;
        const float* s;
        bf16* d;
        size_t off;
        if (i < xtot) {
            size_t w = i / NX;
            off = i - w * NX;
            s = w == 0 ? q : (w == 1 ? k : v);
            d = w == 0 ? qc : (w == 1 ? kc : vc);
        } else {
            size_t j = i - xtot;
            size_t w = j / NW;
            off = j - w * NW;
            s = w == 0 ? Wq : (w == 1 ? Wk : (w == 2 ? Wv : Wo));
            d = w == 0 ? Wqc : (w == 1 ? Wkc : (w == 2 ? Wvc : Woc));
        }
        const float4 x = *(const float4*)(s + off);
        bf16x4 y = {(bf16)x.x, (bf16)x.y, (bf16)x.z, (bf16)x.w};
        *(bf16x4*)(d + off) = y;
    }
}

// Fused Q/K/V^T projections: 768 blocks, XCD-swizzled, no dead blocks.
// wid 0..255: Q = q @ Wq^T; 256..511: K; 512..767: Vt_b = Wv @ v_b^T.
template <bool XB16, bool WB16>
__global__ __launch_bounds__(256) void qkv_proj(
    const float* q32, const float* k32, const float* v32,
    const bf16* q16, const bf16* k16, const bf16* v16,
    const float* Wq32, const float* Wk32, const float* Wv32,
    const bf16* Wq16, const bf16* Wk16, const bf16* Wv16,
    bf16* Qb, bf16* Kb, bf16* Vt) {
    __shared__ bf16 At[128 * 64];
    __shared__ bf16 Bt[128 * 64];
    const int bid = blockIdx.x;
    const int wid = (bid & 7) * 96 + (bid >> 3);  // 768 % 8 == 0: bijective
    if (wid < 512) {
        int s = wid >> 8;  // 0=Q, 1=K
        int t = wid & 255;
        int m0 = (t >> 3) * 128, n0 = (t & 7) * 128;
        gemm_body<XB16, WB16, 4, 4, false>(At, Bt,
                                           s ? k16 : q16, s ? k32 : q32,
                                           s ? Wk16 : Wq16, s ? Wk32 : Wq32,
                                           s ? Kb : Qb, nullptr, nullptr, m0, n0, E, E);
    } else {
        int r = wid - 512;
        int b = r >> 7, rr = r & 127;
        int m0 = (rr >> 4) * 128, n0 = (rr & 15) * 128;
        gemm_body<WB16, XB16, 4, 4, false>(At, Bt,
                                           Wv16, Wv32,
                                           v16 + (size_t)b * T * E, v32 + (size_t)b * T * E,
                                           Vt + (size_t)b * E * T, nullptr, nullptr,
                                           m0, n0, E, T);
    }
}

// Output projection: 64x128 tiles -> 512 blocks (2/CU), fp32 out + bias.
template <bool WB16>
__global__ __launch_bounds__(256) void out_proj(const bf16* Xb, const bf16* W16,
                                                const float* W32, float* Y,
                                                const float* bias) {
    __shared__ bf16 At[64 * 64];
    __shared__ bf16 Bt[128 * 64];
    const int bid = blockIdx.x;
    const int wid = (bid & 7) * 64 + (bid >> 3);  // 512 % 8 == 0: bijective
    const int m0 = (wid >> 3) * 64, n0 = (wid & 7) * 128;
    gemm_body<true, WB16, 2, 4, true>(At, Bt, Xb, nullptr, W16, W32, nullptr, Y, bias,
                                      m0, n0, E, E);
}

// ---------------- Attention: swapped-QK^T 32x32 structure ------------------
__device__ __forceinline__ uint pkbf(float a, float b) {
    uint16_t x = __builtin_bit_cast(uint16_t, (bf16)a);
    uint16_t y = __builtin_bit_cast(uint16_t, (bf16)b);
    return (uint)x | ((uint)y << 16);
}

template <bool DIAG>
__device__ __forceinline__ void attn_tile(int kb, int q0, int l31, int hi,
                                          const bf16* __restrict__ Kp,
                                          const bf16* __restrict__ Vp,
                                          const bf16x8 (&qf)[4],
                                          f32x16& o0, f32x16& o1, float& m, float& l) {
    bf16x8 kf[4];
#pragma unroll
    for (int t = 0; t < 4; ++t)
        kf[t] = *(const bf16x8*)(Kp + (size_t)(kb + l31) * E + t * 16 + hi * 8);
    bf16x8 vf[2][2];
#pragma unroll
    for (int db = 0; db < 2; ++db)
#pragma unroll
        for (int c = 0; c < 2; ++c)
            vf[db][c] = *(const bf16x8*)(Vp + (size_t)(db * 32 + l31) * T + kb + c * 16 + hi * 8);

    f32x16 s = {};
#pragma unroll
    for (int t = 0; t < 4; ++t) s = MFMA32(kf[t], qf[t], s);

    float sv[16];
#pragma unroll
    for (int r = 0; r < 16; ++r) {
        float x = s[r] * 0.125f;
        if constexpr (DIAG) {
            int key = (r & 3) + 8 * (r >> 2) + 4 * hi;
            if (key > l31) x = -1e30f;
        }
        sv[r] = x;
    }
    float pm = sv[0];
#pragma unroll
    for (int r = 1; r < 16; ++r) pm = fmaxf(pm, sv[r]);
    pm = fmaxf(pm, __shfl_xor(pm, 32, 64));

    if (!__all(pm - m <= 8.0f)) {  // deferred rescale (T13)
        float mn = fmaxf(m, pm);
        float al = __expf(m - mn);
        m = mn;
        l *= al;
#pragma unroll
        for (int r = 0; r < 16; ++r) {
            int qr = (r & 3) + 8 * (r >> 2) + 4 * hi;
            float aq = __shfl(al, qr, 64);
            o0[r] *= aq;
            o1[r] *= aq;
        }
    }
    float p[16];
    float ps = 0.f;
#pragma unroll
    for (int r = 0; r < 16; ++r) {
        p[r] = __expf(sv[r] - m);
        ps += p[r];
    }
    l += ps + __shfl_xor(ps, 32, 64);

#pragma unroll
    for (int cc = 0; cc < 2; ++cc) {
        int bse = cc * 8;
        uint x0 = pkbf(p[bse + 0], p[bse + 1]);
        uint x1 = pkbf(p[bse + 2], p[bse + 3]);
        uint y0 = pkbf(p[bse + 4], p[bse + 5]);
        uint y1 = pkbf(p[bse + 6], p[bse + 7]);
        uint sx0 = __shfl_xor(x0, 32, 64), sx1 = __shfl_xor(x1, 32, 64);
        uint sy0 = __shfl_xor(y0, 32, 64), sy1 = __shfl_xor(y1, 32, 64);
        u32x4 wv;
        wv.x = hi ? sy0 : x0;
        wv.y = hi ? sy1 : x1;
        wv.z = hi ? y0 : sx0;
        wv.w = hi ? y1 : sx1;
        bf16x8 pa = __builtin_bit_cast(bf16x8, wv);
        o0 = MFMA32(pa, vf[0][cc], o0);
        o1 = MFMA32(pa, vf[1][cc], o1);
    }
}

__global__ __launch_bounds__(64) void attn_fwd(const bf16* __restrict__ Q,
                                               const bf16* __restrict__ K,
                                               const bf16* __restrict__ Vt,
                                               bf16* __restrict__ O) {
    const int g = blockIdx.x;
    const int xcd = g & 7, j = g >> 3;
    const int hb = xcd * 4 + (j >> 6);
    const int qt = 63 - (j & 63);
    const int h = hb & 15, b = hb >> 4;

    const int lane = threadIdx.x & 63;
    const int l31 = lane & 31, hi = lane >> 5;
    const int q0 = qt * 32;

    const bf16* Qp = Q + (size_t)b * T * E + h * Dh;
    const bf16* Kp = K + (size_t)b * T * E + h * Dh;
    const bf16* Vp = Vt + ((size_t)b * E + h * Dh) * T;

    bf16x8 qf[4];
#pragma unroll
    for (int t = 0; t < 4; ++t)
        qf[t] = *(const bf16x8*)(Qp + (size_t)(q0 + l31) * E + t * 16 + hi * 8);

    f32x16 o0 = {}, o1 = {};
    float m = -1e30f, l = 0.f;

    for (int kt = 0; kt < qt; ++kt)
        attn_tile<false>(kt * 32, q0, l31, hi, Kp, Vp, qf, o0, o1, m, l);
    attn_tile<true>(qt * 32, q0, l31, hi, Kp, Vp, qf, o0, o1, m, l);

    bf16* Op = O + (size_t)b * T * E + h * Dh;
#pragma unroll
    for (int r = 0; r < 16; ++r) {
        int qr = (r & 3) + 8 * (r >> 2) + 4 * hi;
        float lq = __shfl(l, qr, 64);
        float inv = 1.0f / lq;
        Op[(size_t)(q0 + qr) * E + l31] = (bf16)(o0[r] * inv);
        Op[(size_t)(q0 + qr) * E + 32 + l31] = (bf16)(o1[r] * inv);
    }
}

extern "C" void kernel_launch(void* const* d_in, const int* in_sizes, int n_in,
                              void* d_out, int out_size, void* d_ws, size_t ws_size,
                              hipStream_t stream) {
    const float* k_in = (const float*)d_in[0];
    const float* q_in = (const float*)d_in[1];
    const float* v_in = (const float*)d_in[2];
    const float* Wk = (const float*)d_in[3];
    const float* Wq = (const float*)d_in[4];
    const float* Wv = (const float*)d_in[5];
    const float* Wo = (const float*)d_in[6];
    const float* bo = (const float*)d_in[7];
    float* out = (float*)d_out;

    const size_t NE = (size_t)Bsz * T * E;  // 4M
    const size_t NW = (size_t)E * E;        // 1M
    bf16* ws = (bf16*)d_ws;
    bf16* Qb = ws;            // [B*T][E]
    bf16* Kb = ws + NE;       // [B*T][E]
    bf16* Vt = ws + 2 * NE;   // [B][E][T]
    bf16* Ab = ws + 3 * NE;   // attn out; also aliases qc (dead by then)
    bf16* Wqc = ws + 4 * NE;
    bf16* Wkc = Wqc + NW;
    bf16* Wvc = Wkc + NW;
    bf16* Woc = Wvc + NW;
    bf16* qc = Ab;            // alias: qc dead after qkv_proj, Ab written after
    bf16* kc = ws + 4 * NE + 4 * NW;
    bf16* vc = kc + NE;

    const bool planA = ws_size >= (4 * NE + 4 * NW + 2 * NE) * sizeof(bf16);  // 56 MB
    const bool planB = ws_size >= (4 * NE + 4 * NW) * sizeof(bf16);           // 40 MB

    if (planA) {
        cvt_all<<<2048, 256, 0, stream>>>(q_in, k_in, v_in, Wq, Wk, Wv, Wo,
                                          qc, kc, vc, Wqc, Wkc, Wvc, Woc, 1);
        qkv_proj<true, true><<<768, 256, 0, stream>>>(
            nullptr, nullptr, nullptr, qc, kc, vc,
            nullptr, nullptr, nullptr, Wqc, Wkc, Wvc, Qb, Kb, Vt);
    } else if (planB) {
        cvt_all<<<2048, 256, 0, stream>>>(q_in, k_in, v_in, Wq, Wk, Wv, Wo,
                                          nullptr, nullptr, nullptr, Wqc, Wkc, Wvc, Woc, 0);
        qkv_proj<false, true><<<768, 256, 0, stream>>>(
            q_in, k_in, v_in, nullptr, nullptr, nullptr,
            nullptr, nullptr, nullptr, Wqc, Wkc, Wvc, Qb, Kb, Vt);
    } else {
        qkv_proj<false, false><<<768, 256, 0, stream>>>(
            q_in, k_in, v_in, nullptr, nullptr, nullptr,
            Wq, Wk, Wv, nullptr, nullptr, nullptr, Qb, Kb, Vt);
    }

    attn_fwd<<<dim3(64 * H * Bsz), 64, 0, stream>>>(Qb, Kb, Vt, Ab);

    if (planB)
        out_proj<true><<<512, 256, 0, stream>>>(Ab, Woc, nullptr, out, bo);
    else
        out_proj<false><<<512, 256, 0, stream>>>(Ab, nullptr, Wo, out, bo);
}

// Round 4
// 162.117 us; speedup vs baseline: 1.9044x; 1.1145x over previous
//
#include <hip/hip_runtime.h>
#include <stdint.h>

typedef __bf16 bf16;
typedef bf16 bf16x8 __attribute__((ext_vector_type(8)));
typedef bf16 bf16x4 __attribute__((ext_vector_type(4)));
typedef float f32x4 __attribute__((ext_vector_type(4)));
typedef float f32x16 __attribute__((ext_vector_type(16)));
typedef unsigned int uint;
typedef uint u32x4 __attribute__((ext_vector_type(4)));

#define MFMA16(a, b, c) __builtin_amdgcn_mfma_f32_16x16x32_bf16(a, b, c, 0, 0, 0)
#define MFMA32(a, b, c) __builtin_amdgcn_mfma_f32_32x32x16_bf16(a, b, c, 0, 0, 0)

static constexpr int Bsz = 2, T = 2048, E = 1024, H = 16, Dh = 64;
// softmax scale folded into Q at projection; exp2-domain: 1/sqrt(64) * log2(e)
static constexpr float QSCALE = 0.125f * 1.44269504088896f;

__device__ __forceinline__ float exp2fast(float x) {
#if __has_builtin(__builtin_amdgcn_exp2f)
    return __builtin_amdgcn_exp2f(x);
#else
    return exp2f(x);
#endif
}

// async global->LDS, 16B per lane. LDS dest must be wave-uniform base (HW adds lane*16).
__device__ __forceinline__ void gll16(const bf16* g, bf16* l) {
    __builtin_amdgcn_global_load_lds((const __attribute__((address_space(1))) uint*)g,
                                     (__attribute__((address_space(3))) uint*)l, 16, 0, 0);
}

// ---- staging: ROWS x 64 bf16 tile into linear LDS ([row][64], 128B rows) ----
template <int ROWS>
__device__ __forceinline__ void stage_b16(bf16* lds, const bf16* g, int ldg, int wave, int lane) {
#pragma unroll
    for (int i = 0; i < ROWS / 32; ++i) {
        const int row = wave * (ROWS / 4) + i * 8;  // wave-uniform
        gll16(g + (size_t)(row + (lane >> 3)) * ldg + (lane & 7) * 8, lds + row * 64);
    }
}
template <int ROWS>
__device__ __forceinline__ void stage_f32(bf16* lds, const float* g, int ldg, int tid) {
#pragma unroll
    for (int i = 0; i < ROWS / 16; ++i) {
        int gg = tid + i * 256;
        int row = gg >> 4, c4 = (gg & 15) << 2;
        const float4 v = *(const float4*)(g + (size_t)row * ldg + c4);
        bf16x4 bv = {(bf16)v.x, (bf16)v.y, (bf16)v.z, (bf16)v.w};
        *(bf16x4*)(lds + row * 64 + c4) = bv;
    }
}

// ------------- GEMM body: Y[M,N] = A[M,K] @ B[N,K]^T (+bias) ---------------
template <bool AB16, bool BB16, int MF, int NF, bool OUTF32>
__device__ __forceinline__ void gemm_body(bf16* At, bf16* Bt,
                                          const bf16* A16, const float* A32,
                                          const bf16* B16, const float* B32,
                                          bf16* Yb, float* Yf, const float* bias,
                                          int m0, int n0, int K, int ldy, float oscale) {
    constexpr int BM = MF * 32, BN = NF * 32;
    const int tid = threadIdx.x, lane = tid & 63, wave = tid >> 6;
    const int wm = wave >> 1, wn = wave & 1;
    const int fr = lane & 15, kg = (lane >> 4) << 3;

    f32x4 acc[MF][NF] = {};

    for (int k0 = 0; k0 < K; k0 += 64) {
        if constexpr (AB16)
            stage_b16<BM>(At, A16 + (size_t)m0 * K + k0, K, wave, lane);
        else
            stage_f32<BM>(At, A32 + (size_t)m0 * K + k0, K, tid);
        if constexpr (BB16)
            stage_b16<BN>(Bt, B16 + (size_t)n0 * K + k0, K, wave, lane);
        else
            stage_f32<BN>(Bt, B32 + (size_t)n0 * K + k0, K, tid);
        __syncthreads();  // compiler drains vmcnt(0) for global_load_lds here
#pragma unroll
        for (int kk = 0; kk < 64; kk += 32) {
            bf16x8 af[MF], bfr[NF];
#pragma unroll
            for (int f = 0; f < MF; ++f)
                af[f] = *(const bf16x8*)(At + (wm * (BM / 2) + f * 16 + fr) * 64 + kk + kg);
#pragma unroll
            for (int f = 0; f < NF; ++f)
                bfr[f] = *(const bf16x8*)(Bt + (wn * (BN / 2) + f * 16 + fr) * 64 + kk + kg);
#pragma unroll
            for (int mf = 0; mf < MF; ++mf)
#pragma unroll
                for (int nf = 0; nf < NF; ++nf)
                    acc[mf][nf] = MFMA16(af[mf], bfr[nf], acc[mf][nf]);
        }
        __syncthreads();
    }
    const int rb = (lane >> 4) << 2;
#pragma unroll
    for (int mf = 0; mf < MF; ++mf)
#pragma unroll
        for (int nf = 0; nf < NF; ++nf) {
            int n = n0 + wn * (BN / 2) + nf * 16 + fr;
            float bn = 0.f;
            if constexpr (OUTF32) bn = bias[n];
#pragma unroll
            for (int r = 0; r < 4; ++r) {
                int mm = m0 + wm * (BM / 2) + mf * 16 + rb + r;
                float v = acc[mf][nf][r];
                if constexpr (OUTF32)
                    Yf[(size_t)mm * ldy + n] = v + bn;
                else
                    Yb[(size_t)mm * ldy + n] = (bf16)(v * oscale);
            }
        }
}

// fp32 -> bf16 conversion pass (x inputs optional). 16M elems max, 4/thread.
__global__ __launch_bounds__(256) void cvt_all(const float* q, const float* k, const float* v,
                                               const float* Wq, const float* Wk,
                                               const float* Wv, const float* Wo,
                                               bf16* qc, bf16* kc, bf16* vc,
                                               bf16* Wqc, bf16* Wkc, bf16* Wvc, bf16* Woc,
                                               int doX) {
    const size_t NX = (size_t)Bsz * T * E;  // 4M
    const size_t NW = (size_t)E * E;        // 1M
    const size_t xtot = doX ? 3 * NX : 0;
    const size_t nwork = (xtot + 4 * NW) >> 2;
    for (size_t t = (size_t)blockIdx.x * 256 + threadIdx.x; t < nwork;
         t += (size_t)gridDim.x * 256) {
        size_t i = t << 2;
        const float* s;
        bf16* d;
        size_t off;
        if (i < xtot) {
            size_t w = i / NX;
            off = i - w * NX;
            s = w == 0 ? q : (w == 1 ? k : v);
            d = w == 0 ? qc : (w == 1 ? kc : vc);
        } else {
            size_t j = i - xtot;
            size_t w = j / NW;
            off = j - w * NW;
            s = w == 0 ? Wq : (w == 1 ? Wk : (w == 2 ? Wv : Wo));
            d = w == 0 ? Wqc : (w == 1 ? Wkc : (w == 2 ? Wvc : Woc));
        }
        const float4 x = *(const float4*)(s + off);
        bf16x4 y = {(bf16)x.x, (bf16)x.y, (bf16)x.z, (bf16)x.w};
        *(bf16x4*)(d + off) = y;
    }
}

// Fused Q/K/V^T projections: 768 blocks, XCD-swizzled, no dead blocks.
template <bool XB16, bool WB16>
__global__ __launch_bounds__(256) void qkv_proj(
    const float* q32, const float* k32, const float* v32,
    const bf16* q16, const bf16* k16, const bf16* v16,
    const float* Wq32, const float* Wk32, const float* Wv32,
    const bf16* Wq16, const bf16* Wk16, const bf16* Wv16,
    bf16* Qb, bf16* Kb, bf16* Vt) {
    __shared__ bf16 At[128 * 64];
    __shared__ bf16 Bt[128 * 64];
    const int bid = blockIdx.x;
    const int wid = (bid & 7) * 96 + (bid >> 3);  // 768 % 8 == 0: bijective
    if (wid < 512) {
        int s = wid >> 8;  // 0=Q (scaled by QSCALE), 1=K
        int t = wid & 255;
        int m0 = (t >> 3) * 128, n0 = (t & 7) * 128;
        gemm_body<XB16, WB16, 4, 4, false>(At, Bt,
                                           s ? k16 : q16, s ? k32 : q32,
                                           s ? Wk16 : Wq16, s ? Wk32 : Wq32,
                                           s ? Kb : Qb, nullptr, nullptr, m0, n0, E, E,
                                           s ? 1.0f : QSCALE);
    } else {
        int r = wid - 512;
        int b = r >> 7, rr = r & 127;
        int m0 = (rr >> 4) * 128, n0 = (rr & 15) * 128;
        gemm_body<WB16, XB16, 4, 4, false>(At, Bt,
                                           Wv16, Wv32,
                                           v16 + (size_t)b * T * E, v32 + (size_t)b * T * E,
                                           Vt + (size_t)b * E * T, nullptr, nullptr,
                                           m0, n0, E, T, 1.0f);
    }
}

// Output projection: 64x128 tiles -> 512 blocks (2/CU), fp32 out + bias.
template <bool WB16>
__global__ __launch_bounds__(256) void out_proj(const bf16* Xb, const bf16* W16,
                                                const float* W32, float* Y,
                                                const float* bias) {
    __shared__ bf16 At[64 * 64];
    __shared__ bf16 Bt[128 * 64];
    const int bid = blockIdx.x;
    const int wid = (bid & 7) * 64 + (bid >> 3);  // 512 % 8 == 0: bijective
    const int m0 = (wid >> 3) * 64, n0 = (wid & 7) * 128;
    gemm_body<true, WB16, 2, 4, true>(At, Bt, Xb, nullptr, W16, W32, nullptr, Y, bias,
                                      m0, n0, E, E, 1.0f);
}

// ---------------- Attention: swapped-QK^T 32x32, in-block split-K ----------
__device__ __forceinline__ uint pkbf(float a, float b) {
    uint16_t x = __builtin_bit_cast(uint16_t, (bf16)a);
    uint16_t y = __builtin_bit_cast(uint16_t, (bf16)b);
    return (uint)x | ((uint)y << 16);
}

// One 32-key x 32-q tile. Scores arrive pre-scaled (QSCALE in Q): exp2 domain.
template <bool DIAG>
__device__ __forceinline__ void attn_tile(int kb, int l31, int hi,
                                          const bf16* __restrict__ Kp,
                                          const bf16* __restrict__ Vp,
                                          const bf16x8 (&qf)[4],
                                          f32x16& o0, f32x16& o1, float& m, float& l) {
    bf16x8 kf[4];
#pragma unroll
    for (int t = 0; t < 4; ++t)
        kf[t] = *(const bf16x8*)(Kp + (size_t)(kb + l31) * E + t * 16 + hi * 8);
    bf16x8 vf[2][2];
#pragma unroll
    for (int db = 0; db < 2; ++db)
#pragma unroll
        for (int c = 0; c < 2; ++c)
            vf[db][c] = *(const bf16x8*)(Vp + (size_t)(db * 32 + l31) * T + kb + c * 16 + hi * 8);

    f32x16 s = {};
#pragma unroll
    for (int t = 0; t < 4; ++t) s = MFMA32(kf[t], qf[t], s);

    float sv[16];
#pragma unroll
    for (int r = 0; r < 16; ++r) {
        float x = s[r];
        if constexpr (DIAG) {
            int key = (r & 3) + 8 * (r >> 2) + 4 * hi;
            if (key > l31) x = -1e30f;
        }
        sv[r] = x;
    }
    float pm = sv[0];
#pragma unroll
    for (int r = 1; r < 16; ++r) pm = fmaxf(pm, sv[r]);
    pm = fmaxf(pm, __shfl_xor(pm, 32, 64));

    if (!__all(pm - m <= 11.5f)) {  // deferred rescale (T13), 8*log2e
        float mn = fmaxf(m, pm);
        float al = exp2fast(m - mn);
        m = mn;
        l *= al;
#pragma unroll
        for (int r = 0; r < 16; ++r) {
            int qr = (r & 3) + 8 * (r >> 2) + 4 * hi;
            float aq = __shfl(al, qr, 64);
            o0[r] *= aq;
            o1[r] *= aq;
        }
    }
    float p[16];
    float ps = 0.f;
#pragma unroll
    for (int r = 0; r < 16; ++r) {
        p[r] = exp2fast(sv[r] - m);
        ps += p[r];
    }
    l += ps + __shfl_xor(ps, 32, 64);

#pragma unroll
    for (int cc = 0; cc < 2; ++cc) {
        int bse = cc * 8;
        uint x0 = pkbf(p[bse + 0], p[bse + 1]);
        uint x1 = pkbf(p[bse + 2], p[bse + 3]);
        uint y0 = pkbf(p[bse + 4], p[bse + 5]);
        uint y1 = pkbf(p[bse + 6], p[bse + 7]);
        uint sx0 = __shfl_xor(x0, 32, 64), sx1 = __shfl_xor(x1, 32, 64);
        uint sy0 = __shfl_xor(y0, 32, 64), sy1 = __shfl_xor(y1, 32, 64);
        u32x4 wv;
        wv.x = hi ? sy0 : x0;
        wv.y = hi ? sy1 : x1;
        wv.z = hi ? y0 : sx0;
        wv.w = hi ? y1 : sx1;
        bf16x8 pa = __builtin_bit_cast(bf16x8, wv);
        o0 = MFMA32(pa, vf[0][cc], o0);
        o1 = MFMA32(pa, vf[1][cc], o1);
    }
}

// 4 waves/block, one 32-row q-tile/block, in-block split-K (wave w: kt=w,w+4,...).
__global__ __launch_bounds__(256) void attn_fwd(const bf16* __restrict__ Q,
                                                const bf16* __restrict__ K,
                                                const bf16* __restrict__ Vt,
                                                bf16* __restrict__ O) {
    __shared__ float oS[4][64 * 18];  // stride 18: 2-way-max bank conflicts
    __shared__ float mS[4][32], lS[4][32];

    const int g = blockIdx.x;
    const int xcd = g & 7, j = g >> 3;            // 2048 % 8 == 0: bijective
    const int hb = xcd * 4 + (j & 3);             // head-batch 0..31
    const int qt = 63 - (j >> 2);                 // heaviest q-tiles first, globally
    const int h = hb & 15, b = hb >> 4;

    const int tid = threadIdx.x, lane = tid & 63, w = tid >> 6;
    const int l31 = lane & 31, hi = lane >> 5;
    const int q0 = qt * 32;

    const bf16* Qp = Q + (size_t)b * T * E + h * Dh;
    const bf16* Kp = K + (size_t)b * T * E + h * Dh;
    const bf16* Vp = Vt + ((size_t)b * E + h * Dh) * T;

    bf16x8 qf[4];
#pragma unroll
    for (int t = 0; t < 4; ++t)
        qf[t] = *(const bf16x8*)(Qp + (size_t)(q0 + l31) * E + t * 16 + hi * 8);

    f32x16 o0 = {}, o1 = {};
    float m = -1e30f, l = 0.f;

    for (int kt = w; kt < qt; kt += 4)
        attn_tile<false>(kt * 32, l31, hi, Kp, Vp, qf, o0, o1, m, l);
    if ((qt & 3) == w)
        attn_tile<true>(q0, l31, hi, Kp, Vp, qf, o0, o1, m, l);

    // ---- in-block combine of 4 split-K partials ----
    if (lane < 32) {
        mS[w][l31] = m;
        lS[w][l31] = l;
    }
    bf16* Op = O + (size_t)b * T * E + h * Dh;
#pragma unroll
    for (int half = 0; half < 2; ++half) {
        const f32x16 oo = half ? o1 : o0;  // static after unroll
        __syncthreads();                   // oS reuse guard (and m/l visibility)
        float* row = oS[w] + lane * 18;
#pragma unroll
        for (int jj = 0; jj < 8; ++jj)
            *(float2*)(row + 2 * jj) = make_float2(oo[2 * jj], oo[2 * jj + 1]);
        __syncthreads();
        // wave w combines r = 4w..4w+3 for all 64 lanes; q = (r&3)+8*(r>>2)+4*hi
#pragma unroll
        for (int t = 0; t < 4; ++t) {
            const int q = t + 8 * w + 4 * hi;
            const int r = 4 * w + t;
            float m0v = mS[0][q], m1 = mS[1][q], m2 = mS[2][q], m3 = mS[3][q];
            float M = fmaxf(fmaxf(m0v, m1), fmaxf(m2, m3));
            float w0 = exp2fast(m0v - M), w1 = exp2fast(m1 - M);
            float w2 = exp2fast(m2 - M), w3 = exp2fast(m3 - M);
            float L = lS[0][q] * w0 + lS[1][q] * w1 + lS[2][q] * w2 + lS[3][q] * w3;
            float val = oS[0][lane * 18 + r] * w0 + oS[1][lane * 18 + r] * w1 +
                        oS[2][lane * 18 + r] * w2 + oS[3][lane * 18 + r] * w3;
            float inv = __builtin_amdgcn_rcpf(L);
            Op[(size_t)(q0 + q) * E + half * 32 + l31] = (bf16)(val * inv);
        }
    }
}

extern "C" void kernel_launch(void* const* d_in, const int* in_sizes, int n_in,
                              void* d_out, int out_size, void* d_ws, size_t ws_size,
                              hipStream_t stream) {
    const float* k_in = (const float*)d_in[0];
    const float* q_in = (const float*)d_in[1];
    const float* v_in = (const float*)d_in[2];
    const float* Wk = (const float*)d_in[3];
    const float* Wq = (const float*)d_in[4];
    const float* Wv = (const float*)d_in[5];
    const float* Wo = (const float*)d_in[6];
    const float* bo = (const float*)d_in[7];
    float* out = (float*)d_out;

    const size_t NE = (size_t)Bsz * T * E;  // 4M
    const size_t NW = (size_t)E * E;        // 1M
    bf16* ws = (bf16*)d_ws;
    bf16* Qb = ws;            // [B*T][E]  (pre-scaled by QSCALE)
    bf16* Kb = ws + NE;       // [B*T][E]
    bf16* Vt = ws + 2 * NE;   // [B][E][T]
    bf16* Ab = ws + 3 * NE;   // attn out; also aliases qc (dead by then)
    bf16* Wqc = ws + 4 * NE;
    bf16* Wkc = Wqc + NW;
    bf16* Wvc = Wkc + NW;
    bf16* Woc = Wvc + NW;
    bf16* qc = Ab;            // alias: qc dead after qkv_proj, Ab written after
    bf16* kc = ws + 4 * NE + 4 * NW;
    bf16* vc = kc + NE;

    const bool planA = ws_size >= (4 * NE + 4 * NW + 2 * NE) * sizeof(bf16);  // 56 MB
    const bool planB = ws_size >= (4 * NE + 4 * NW) * sizeof(bf16);           // 40 MB

    if (planA) {
        cvt_all<<<2048, 256, 0, stream>>>(q_in, k_in, v_in, Wq, Wk, Wv, Wo,
                                          qc, kc, vc, Wqc, Wkc, Wvc, Woc, 1);
        qkv_proj<true, true><<<768, 256, 0, stream>>>(
            nullptr, nullptr, nullptr, qc, kc, vc,
            nullptr, nullptr, nullptr, Wqc, Wkc, Wvc, Qb, Kb, Vt);
    } else if (planB) {
        cvt_all<<<2048, 256, 0, stream>>>(q_in, k_in, v_in, Wq, Wk, Wv, Wo,
                                          nullptr, nullptr, nullptr, Wqc, Wkc, Wvc, Woc, 0);
        qkv_proj<false, true><<<768, 256, 0, stream>>>(
            q_in, k_in, v_in, nullptr, nullptr, nullptr,
            nullptr, nullptr, nullptr, Wqc, Wkc, Wvc, Qb, Kb, Vt);
    } else {
        qkv_proj<false, false><<<768, 256, 0, stream>>>(
            q_in, k_in, v_in, nullptr, nullptr, nullptr,
            Wq, Wk, Wv, nullptr, nullptr, nullptr, Qb, Kb, Vt);
    }

    attn_fwd<<<dim3(2048), 256, 0, stream>>>(Qb, Kb, Vt, Ab);

    if (planB)
        out_proj<true><<<512, 256, 0, stream>>>(Ab, Woc, nullptr, out, bo);
    else
        out_proj<false><<<512, 256, 0, stream>>>(Ab, nullptr, Wo, out, bo);
}

// Round 7
// 160.776 us; speedup vs baseline: 1.9203x; 1.0083x over previous
//
#include <hip/hip_runtime.h>
#include <stdint.h>

typedef __bf16 bf16;
typedef bf16 bf16x8 __attribute__((ext_vector_type(8)));
typedef bf16 bf16x4 __attribute__((ext_vector_type(4)));
typedef float f32x4 __attribute__((ext_vector_type(4)));
typedef float f32x16 __attribute__((ext_vector_type(16)));
typedef unsigned int uint;
typedef uint u32x4 __attribute__((ext_vector_type(4)));

#define MFMA16(a, b, c) __builtin_amdgcn_mfma_f32_16x16x32_bf16(a, b, c, 0, 0, 0)
#define MFMA32(a, b, c) __builtin_amdgcn_mfma_f32_32x32x16_bf16(a, b, c, 0, 0, 0)

static constexpr int Bsz = 2, T = 2048, E = 1024, H = 16, Dh = 64;
// softmax scale folded into Q at projection; exp2-domain: 1/sqrt(64) * log2(e)
static constexpr float QSCALE = 0.125f * 1.44269504088896f;

__device__ __forceinline__ float exp2fast(float x) {
#if __has_builtin(__builtin_amdgcn_exp2f)
    return __builtin_amdgcn_exp2f(x);
#else
    return exp2f(x);
#endif
}

// async global->LDS, 16B per lane. LDS dest must be wave-uniform base (HW adds lane*16).
__device__ __forceinline__ void gll16(const bf16* g, bf16* l) {
    __builtin_amdgcn_global_load_lds((const __attribute__((address_space(1))) uint*)g,
                                     (__attribute__((address_space(3))) uint*)l, 16, 0, 0);
}

// ---- staging: ROWS x 64 bf16 tile into linear LDS ([row][64], 128B rows) ----
template <int ROWS>
__device__ __forceinline__ void stage_b16(bf16* lds, const bf16* g, int ldg, int wave, int lane) {
#pragma unroll
    for (int i = 0; i < ROWS / 32; ++i) {
        const int row = wave * (ROWS / 4) + i * 8;  // wave-uniform
        gll16(g + (size_t)(row + (lane >> 3)) * ldg + (lane & 7) * 8, lds + row * 64);
    }
}
template <int ROWS>
__device__ __forceinline__ void stage_f32(bf16* lds, const float* g, int ldg, int tid) {
#pragma unroll
    for (int i = 0; i < ROWS / 16; ++i) {
        int gg = tid + i * 256;
        int row = gg >> 4, c4 = (gg & 15) << 2;
        const float4 v = *(const float4*)(g + (size_t)row * ldg + c4);
        bf16x4 bv = {(bf16)v.x, (bf16)v.y, (bf16)v.z, (bf16)v.w};
        *(bf16x4*)(lds + row * 64 + c4) = bv;
    }
}

// ------------- GEMM body: Y[M,N] = A[M,K] @ B[N,K]^T (+bias) ---------------
template <bool AB16, bool BB16, int MF, int NF, bool OUTF32>
__device__ __forceinline__ void gemm_body(bf16* At, bf16* Bt,
                                          const bf16* A16, const float* A32,
                                          const bf16* B16, const float* B32,
                                          bf16* Yb, float* Yf, const float* bias,
                                          int m0, int n0, int K, int ldy, float oscale) {
    constexpr int BM = MF * 32, BN = NF * 32;
    const int tid = threadIdx.x, lane = tid & 63, wave = tid >> 6;
    const int wm = wave >> 1, wn = wave & 1;
    const int fr = lane & 15, kg = (lane >> 4) << 3;

    f32x4 acc[MF][NF] = {};

    for (int k0 = 0; k0 < K; k0 += 64) {
        if constexpr (AB16)
            stage_b16<BM>(At, A16 + (size_t)m0 * K + k0, K, wave, lane);
        else
            stage_f32<BM>(At, A32 + (size_t)m0 * K + k0, K, tid);
        if constexpr (BB16)
            stage_b16<BN>(Bt, B16 + (size_t)n0 * K + k0, K, wave, lane);
        else
            stage_f32<BN>(Bt, B32 + (size_t)n0 * K + k0, K, tid);
        __syncthreads();  // compiler drains vmcnt(0) for global_load_lds here
#pragma unroll
        for (int kk = 0; kk < 64; kk += 32) {
            bf16x8 af[MF], bfr[NF];
#pragma unroll
            for (int f = 0; f < MF; ++f)
                af[f] = *(const bf16x8*)(At + (wm * (BM / 2) + f * 16 + fr) * 64 + kk + kg);
#pragma unroll
            for (int f = 0; f < NF; ++f)
                bfr[f] = *(const bf16x8*)(Bt + (wn * (BN / 2) + f * 16 + fr) * 64 + kk + kg);
#pragma unroll
            for (int mf = 0; mf < MF; ++mf)
#pragma unroll
                for (int nf = 0; nf < NF; ++nf)
                    acc[mf][nf] = MFMA16(af[mf], bfr[nf], acc[mf][nf]);
        }
        __syncthreads();
    }
    const int rb = (lane >> 4) << 2;
#pragma unroll
    for (int mf = 0; mf < MF; ++mf)
#pragma unroll
        for (int nf = 0; nf < NF; ++nf) {
            int n = n0 + wn * (BN / 2) + nf * 16 + fr;
            float bn = 0.f;
            if constexpr (OUTF32) bn = bias[n];
#pragma unroll
            for (int r = 0; r < 4; ++r) {
                int mm = m0 + wm * (BM / 2) + mf * 16 + rb + r;
                float v = acc[mf][nf][r];
                if constexpr (OUTF32)
                    Yf[(size_t)mm * ldy + n] = v + bn;
                else
                    Yb[(size_t)mm * ldy + n] = (bf16)(v * oscale);
            }
        }
}

// fp32 -> bf16 conversion pass (x inputs optional). 16M elems max, 4/thread.
__global__ __launch_bounds__(256) void cvt_all(const float* q, const float* k, const float* v,
                                               const float* Wq, const float* Wk,
                                               const float* Wv, const float* Wo,
                                               bf16* qc, bf16* kc, bf16* vc,
                                               bf16* Wqc, bf16* Wkc, bf16* Wvc, bf16* Woc,
                                               int doX) {
    const size_t NX = (size_t)Bsz * T * E;  // 4M
    const size_t NW = (size_t)E * E;        // 1M
    const size_t xtot = doX ? 3 * NX : 0;
    const size_t nwork = (xtot + 4 * NW) >> 2;
    for (size_t t = (size_t)blockIdx.x * 256 + threadIdx.x; t < nwork;
         t += (size_t)gridDim.x * 256) {
        size_t i = t << 2;
        const float* s;
        bf16* d;
        size_t off;
        if (i < xtot) {
            size_t w = i / NX;
            off = i - w * NX;
            s = w == 0 ? q : (w == 1 ? k : v);
            d = w == 0 ? qc : (w == 1 ? kc : vc);
        } else {
            size_t j = i - xtot;
            size_t w = j / NW;
            off = j - w * NW;
            s = w == 0 ? Wq : (w == 1 ? Wk : (w == 2 ? Wv : Wo));
            d = w == 0 ? Wqc : (w == 1 ? Wkc : (w == 2 ? Wvc : Woc));
        }
        const float4 x = *(const float4*)(s + off);
        bf16x4 y = {(bf16)x.x, (bf16)x.y, (bf16)x.z, (bf16)x.w};
        *(bf16x4*)(d + off) = y;
    }
}

// Fused Q/K/V^T projections: 768 blocks, XCD-swizzled, no dead blocks.
template <bool XB16, bool WB16>
__global__ __launch_bounds__(256) void qkv_proj(
    const float* q32, const float* k32, const float* v32,
    const bf16* q16, const bf16* k16, const bf16* v16,
    const float* Wq32, const float* Wk32, const float* Wv32,
    const bf16* Wq16, const bf16* Wk16, const bf16* Wv16,
    bf16* Qb, bf16* Kb, bf16* Vt) {
    __shared__ bf16 At[128 * 64];
    __shared__ bf16 Bt[128 * 64];
    const int bid = blockIdx.x;
    const int wid = (bid & 7) * 96 + (bid >> 3);  // 768 % 8 == 0: bijective
    if (wid < 512) {
        int s = wid >> 8;  // 0=Q (scaled by QSCALE), 1=K
        int t = wid & 255;
        int m0 = (t >> 3) * 128, n0 = (t & 7) * 128;
        gemm_body<XB16, WB16, 4, 4, false>(At, Bt,
                                           s ? k16 : q16, s ? k32 : q32,
                                           s ? Wk16 : Wq16, s ? Wk32 : Wq32,
                                           s ? Kb : Qb, nullptr, nullptr, m0, n0, E, E,
                                           s ? 1.0f : QSCALE);
    } else {
        int r = wid - 512;
        int b = r >> 7, rr = r & 127;
        int m0 = (rr >> 4) * 128, n0 = (rr & 15) * 128;
        gemm_body<WB16, XB16, 4, 4, false>(At, Bt,
                                           Wv16, Wv32,
                                           v16 + (size_t)b * T * E, v32 + (size_t)b * T * E,
                                           Vt + (size_t)b * E * T, nullptr, nullptr,
                                           m0, n0, E, T, 1.0f);
    }
}

// Output projection: 64x128 tiles -> 512 blocks (2/CU), fp32 out + bias.
template <bool WB16>
__global__ __launch_bounds__(256) void out_proj(const bf16* Xb, const bf16* W16,
                                                const float* W32, float* Y,
                                                const float* bias) {
    __shared__ bf16 At[64 * 64];
    __shared__ bf16 Bt[128 * 64];
    const int bid = blockIdx.x;
    const int wid = (bid & 7) * 64 + (bid >> 3);  // 512 % 8 == 0: bijective
    const int m0 = (wid >> 3) * 64, n0 = (wid & 7) * 128;
    gemm_body<true, WB16, 2, 4, true>(At, Bt, Xb, nullptr, W16, W32, nullptr, Y, bias,
                                      m0, n0, E, E, 1.0f);
}

// ---------------- Attention: swapped-QK^T 32x32, in-block split-K ----------
__device__ __forceinline__ uint pkbf(float a, float b) {
    uint16_t x = __builtin_bit_cast(uint16_t, (bf16)a);
    uint16_t y = __builtin_bit_cast(uint16_t, (bf16)b);
    return (uint)x | ((uint)y << 16);
}

// One 32-key x 32-q tile. kf holds this tile's K on entry; after QK^T it is
// refilled with the NEXT tile's K (nextkb>=0) -> load latency hides under
// softmax+PV. Scores arrive pre-scaled (QSCALE folded into Q): exp2 domain.
// All cross-half exchanges via __shfl_xor (round-4 verified; permlane32_swap
// with self-operand is unsound: RA may coalesce both inputs onto one VGPR).
template <bool DIAG>
__device__ __forceinline__ void attn_tile(int kb, int nextkb, int l31, int hi,
                                          const bf16* __restrict__ Kp,
                                          const bf16* __restrict__ Vp,
                                          const bf16x8 (&qf)[4], bf16x8 (&kf)[4],
                                          f32x16& o0, f32x16& o1, float& m, float& l) {
    // V loads for this tile (consumed at PV ~500 cyc later)
    bf16x8 vf[2][2];
#pragma unroll
    for (int db = 0; db < 2; ++db)
#pragma unroll
        for (int c = 0; c < 2; ++c)
            vf[db][c] = *(const bf16x8*)(Vp + (size_t)(db * 32 + l31) * T + kb + c * 16 + hi * 8);

    // QK^T
    __builtin_amdgcn_s_setprio(1);
    f32x16 s = {};
#pragma unroll
    for (int t = 0; t < 4; ++t) s = MFMA32(kf[t], qf[t], s);
    __builtin_amdgcn_s_setprio(0);

    // kf registers are dead now: prefetch next tile's K into them
    if (nextkb >= 0) {
#pragma unroll
        for (int t = 0; t < 4; ++t)
            kf[t] = *(const bf16x8*)(Kp + (size_t)(nextkb + l31) * E + t * 16 + hi * 8);
    }

    float sv[16];
#pragma unroll
    for (int r = 0; r < 16; ++r) {
        float x = s[r];
        if constexpr (DIAG) {
            int key = (r & 3) + 8 * (r >> 2) + 4 * hi;
            if (key > l31) x = -1e30f;
        }
        sv[r] = x;
    }
    float pm = sv[0];
#pragma unroll
    for (int r = 1; r < 16; ++r) pm = fmaxf(pm, sv[r]);
    pm = fmaxf(pm, __shfl_xor(pm, 32, 64));  // cross-half max

    if (!__all(pm - m <= 11.5f)) {  // deferred rescale (T13), 8*log2e
        float mn = fmaxf(m, pm);
        float al = exp2fast(m - mn);
        m = mn;
        l *= al;
#pragma unroll
        for (int r = 0; r < 16; ++r) {
            int qr = (r & 3) + 8 * (r >> 2) + 4 * hi;
            float aq = __shfl(al, qr, 64);
            o0[r] *= aq;
            o1[r] *= aq;
        }
    }
    float p[16];
    float ps = 0.f;
#pragma unroll
    for (int r = 0; r < 16; ++r) {
        p[r] = exp2fast(sv[r] - m);
        ps += p[r];
    }
    l += ps + __shfl_xor(ps, 32, 64);  // cross-half sum

    // P -> PV A-fragments (round-4 verified shfl_xor routing)
    __builtin_amdgcn_s_setprio(1);
#pragma unroll
    for (int cc = 0; cc < 2; ++cc) {
        int bse = cc * 8;
        uint x0 = pkbf(p[bse + 0], p[bse + 1]);
        uint x1 = pkbf(p[bse + 2], p[bse + 3]);
        uint y0 = pkbf(p[bse + 4], p[bse + 5]);
        uint y1 = pkbf(p[bse + 6], p[bse + 7]);
        uint sx0 = __shfl_xor(x0, 32, 64), sx1 = __shfl_xor(x1, 32, 64);
        uint sy0 = __shfl_xor(y0, 32, 64), sy1 = __shfl_xor(y1, 32, 64);
        u32x4 wv;
        wv.x = hi ? sy0 : x0;
        wv.y = hi ? sy1 : x1;
        wv.z = hi ? y0 : sx0;
        wv.w = hi ? y1 : sx1;
        bf16x8 pa = __builtin_bit_cast(bf16x8, wv);
        o0 = MFMA32(pa, vf[0][cc], o0);
        o1 = MFMA32(pa, vf[1][cc], o1);
    }
    __builtin_amdgcn_s_setprio(0);
}

// 4 waves/block, one 32-row q-tile/block, in-block split-K (wave w: kt=w,w+4,...).
__global__ __launch_bounds__(256) void attn_fwd(const bf16* __restrict__ Q,
                                                const bf16* __restrict__ K,
                                                const bf16* __restrict__ Vt,
                                                bf16* __restrict__ O) {
    __shared__ float oS[4][64 * 18];  // stride 18: 2-way-max bank conflicts
    __shared__ float mS[4][32], lS[4][32];

    const int g = blockIdx.x;
    const int xcd = g & 7, j = g >> 3;            // 2048 % 8 == 0: bijective
    const int hb = xcd * 4 + (j & 3);             // head-batch 0..31
    const int qt = 63 - (j >> 2);                 // heaviest q-tiles first, globally
    const int h = hb & 15, b = hb >> 4;

    const int tid = threadIdx.x, lane = tid & 63, w = tid >> 6;
    const int l31 = lane & 31, hi = lane >> 5;
    const int q0 = qt * 32;

    const bf16* Qp = Q + (size_t)b * T * E + h * Dh;
    const bf16* Kp = K + (size_t)b * T * E + h * Dh;
    const bf16* Vp = Vt + ((size_t)b * E + h * Dh) * T;

    bf16x8 qf[4];
#pragma unroll
    for (int t = 0; t < 4; ++t)
        qf[t] = *(const bf16x8*)(Qp + (size_t)(q0 + l31) * E + t * 16 + hi * 8);

    f32x16 o0 = {}, o1 = {};
    float m = -1e30f, l = 0.f;

    const bool dg = ((qt & 3) == w);
    bf16x8 kf[4];
    const int first = (w < qt) ? w * 32 : (dg ? q0 : -1);
    if (first >= 0) {
#pragma unroll
        for (int t = 0; t < 4; ++t)
            kf[t] = *(const bf16x8*)(Kp + (size_t)(first + l31) * E + t * 16 + hi * 8);
    }
    for (int kt = w; kt < qt; kt += 4) {
        const int kn = kt + 4;
        const int nextkb = (kn < qt) ? kn * 32 : (dg ? q0 : -1);
        attn_tile<false>(kt * 32, nextkb, l31, hi, Kp, Vp, qf, kf, o0, o1, m, l);
    }
    if (dg)
        attn_tile<true>(q0, -1, l31, hi, Kp, Vp, qf, kf, o0, o1, m, l);

    // ---- in-block combine of 4 split-K partials ----
    if (lane < 32) {
        mS[w][l31] = m;
        lS[w][l31] = l;
    }
    bf16* Op = O + (size_t)b * T * E + h * Dh;
#pragma unroll
    for (int half = 0; half < 2; ++half) {
        const f32x16 oo = half ? o1 : o0;  // static after unroll
        __syncthreads();                   // oS reuse guard (and m/l visibility)
        float* row = oS[w] + lane * 18;
#pragma unroll
        for (int jj = 0; jj < 8; ++jj)
            *(float2*)(row + 2 * jj) = make_float2(oo[2 * jj], oo[2 * jj + 1]);
        __syncthreads();
        // wave w combines r = 4w..4w+3 for all 64 lanes; q = (r&3)+8*(r>>2)+4*hi
#pragma unroll
        for (int t = 0; t < 4; ++t) {
            const int q = t + 8 * w + 4 * hi;
            const int r = 4 * w + t;
            float m0v = mS[0][q], m1 = mS[1][q], m2 = mS[2][q], m3 = mS[3][q];
            float M = fmaxf(fmaxf(m0v, m1), fmaxf(m2, m3));
            float w0 = exp2fast(m0v - M), w1 = exp2fast(m1 - M);
            float w2 = exp2fast(m2 - M), w3 = exp2fast(m3 - M);
            float L = lS[0][q] * w0 + lS[1][q] * w1 + lS[2][q] * w2 + lS[3][q] * w3;
            float val = oS[0][lane * 18 + r] * w0 + oS[1][lane * 18 + r] * w1 +
                        oS[2][lane * 18 + r] * w2 + oS[3][lane * 18 + r] * w3;
            float inv = __builtin_amdgcn_rcpf(L);
            Op[(size_t)(q0 + q) * E + half * 32 + l31] = (bf16)(val * inv);
        }
    }
}

extern "C" void kernel_launch(void* const* d_in, const int* in_sizes, int n_in,
                              void* d_out, int out_size, void* d_ws, size_t ws_size,
                              hipStream_t stream) {
    const float* k_in = (const float*)d_in[0];
    const float* q_in = (const float*)d_in[1];
    const float* v_in = (const float*)d_in[2];
    const float* Wk = (const float*)d_in[3];
    const float* Wq = (const float*)d_in[4];
    const float* Wv = (const float*)d_in[5];
    const float* Wo = (const float*)d_in[6];
    const float* bo = (const float*)d_in[7];
    float* out = (float*)d_out;

    const size_t NE = (size_t)Bsz * T * E;  // 4M
    const size_t NW = (size_t)E * E;        // 1M
    bf16* ws = (bf16*)d_ws;
    bf16* Qb = ws;            // [B*T][E]  (pre-scaled by QSCALE)
    bf16* Kb = ws + NE;       // [B*T][E]
    bf16* Vt = ws + 2 * NE;   // [B][E][T]
    bf16* Ab = ws + 3 * NE;   // attn out; also aliases qc (dead by then)
    bf16* Wqc = ws + 4 * NE;
    bf16* Wkc = Wqc + NW;
    bf16* Wvc = Wkc + NW;
    bf16* Woc = Wvc + NW;
    bf16* qc = Ab;            // alias: qc dead after qkv_proj, Ab written after
    bf16* kc = ws + 4 * NE + 4 * NW;
    bf16* vc = kc + NE;

    const bool planA = ws_size >= (4 * NE + 4 * NW + 2 * NE) * sizeof(bf16);  // 56 MB
    const bool planB = ws_size >= (4 * NE + 4 * NW) * sizeof(bf16);           // 40 MB

    if (planA) {
        cvt_all<<<2048, 256, 0, stream>>>(q_in, k_in, v_in, Wq, Wk, Wv, Wo,
                                          qc, kc, vc, Wqc, Wkc, Wvc, Woc, 1);
        qkv_proj<true, true><<<768, 256, 0, stream>>>(
            nullptr, nullptr, nullptr, qc, kc, vc,
            nullptr, nullptr, nullptr, Wqc, Wkc, Wvc, Qb, Kb, Vt);
    } else if (planB) {
        cvt_all<<<2048, 256, 0, stream>>>(q_in, k_in, v_in, Wq, Wk, Wv, Wo,
                                          nullptr, nullptr, nullptr, Wqc, Wkc, Wvc, Woc, 0);
        qkv_proj<false, true><<<768, 256, 0, stream>>>(
            q_in, k_in, v_in, nullptr, nullptr, nullptr,
            nullptr, nullptr, nullptr, Wqc, Wkc, Wvc, Qb, Kb, Vt);
    } else {
        qkv_proj<false, false><<<768, 256, 0, stream>>>(
            q_in, k_in, v_in, nullptr, nullptr, nullptr,
            Wq, Wk, Wv, nullptr, nullptr, nullptr, Qb, Kb, Vt);
    }

    attn_fwd<<<dim3(2048), 256, 0, stream>>>(Qb, Kb, Vt, Ab);

    if (planB)
        out_proj<true><<<512, 256, 0, stream>>>(Ab, Woc, nullptr, out, bo);
    else
        out_proj<false><<<512, 256, 0, stream>>>(Ab, nullptr, Wo, out, bo);
}

// Round 8
// 159.310 us; speedup vs baseline: 1.9379x; 1.0092x over previous
//
#include <hip/hip_runtime.h>
#include <stdint.h>

typedef __bf16 bf16;
typedef bf16 bf16x8 __attribute__((ext_vector_type(8)));
typedef bf16 bf16x4 __attribute__((ext_vector_type(4)));
typedef float f32x4 __attribute__((ext_vector_type(4)));
typedef float f32x16 __attribute__((ext_vector_type(16)));
typedef unsigned int uint;
typedef uint u32x4 __attribute__((ext_vector_type(4)));

#define MFMA16(a, b, c) __builtin_amdgcn_mfma_f32_16x16x32_bf16(a, b, c, 0, 0, 0)
#define MFMA32(a, b, c) __builtin_amdgcn_mfma_f32_32x32x16_bf16(a, b, c, 0, 0, 0)

static constexpr int Bsz = 2, T = 2048, E = 1024, H = 16, Dh = 64;
// softmax scale folded into Q at projection; exp2-domain: 1/sqrt(64) * log2(e)
static constexpr float QSCALE = 0.125f * 1.44269504088896f;

__device__ __forceinline__ float exp2fast(float x) {
#if __has_builtin(__builtin_amdgcn_exp2f)
    return __builtin_amdgcn_exp2f(x);
#else
    return exp2f(x);
#endif
}

// async global->LDS, 16B per lane. LDS dest must be wave-uniform base (HW adds lane*16).
__device__ __forceinline__ void gll16(const bf16* g, bf16* l) {
    __builtin_amdgcn_global_load_lds((const __attribute__((address_space(1))) uint*)g,
                                     (__attribute__((address_space(3))) uint*)l, 16, 0, 0);
}

// ---- staging: ROWS x 64 bf16 tile into linear LDS ([row][64], 128B rows) ----
template <int ROWS>
__device__ __forceinline__ void stage_b16(bf16* lds, const bf16* g, int ldg, int wave, int lane) {
#pragma unroll
    for (int i = 0; i < ROWS / 32; ++i) {
        const int row = wave * (ROWS / 4) + i * 8;  // wave-uniform
        gll16(g + (size_t)(row + (lane >> 3)) * ldg + (lane & 7) * 8, lds + row * 64);
    }
}
template <int ROWS>
__device__ __forceinline__ void stage_f32(bf16* lds, const float* g, int ldg, int tid) {
#pragma unroll
    for (int i = 0; i < ROWS / 16; ++i) {
        int gg = tid + i * 256;
        int row = gg >> 4, c4 = (gg & 15) << 2;
        const float4 v = *(const float4*)(g + (size_t)row * ldg + c4);
        bf16x4 bv = {(bf16)v.x, (bf16)v.y, (bf16)v.z, (bf16)v.w};
        *(bf16x4*)(lds + row * 64 + c4) = bv;
    }
}

// ------------- GEMM body: Y[M,N] = A[M,K] @ B[N,K]^T (+bias) ---------------
template <bool AB16, bool BB16, int MF, int NF, bool OUTF32>
__device__ __forceinline__ void gemm_body(bf16* At, bf16* Bt,
                                          const bf16* A16, const float* A32,
                                          const bf16* B16, const float* B32,
                                          bf16* Yb, float* Yf, const float* bias,
                                          int m0, int n0, int K, int ldy, float oscale) {
    constexpr int BM = MF * 32, BN = NF * 32;
    const int tid = threadIdx.x, lane = tid & 63, wave = tid >> 6;
    const int wm = wave >> 1, wn = wave & 1;
    const int fr = lane & 15, kg = (lane >> 4) << 3;

    f32x4 acc[MF][NF] = {};

    for (int k0 = 0; k0 < K; k0 += 64) {
        if constexpr (AB16)
            stage_b16<BM>(At, A16 + (size_t)m0 * K + k0, K, wave, lane);
        else
            stage_f32<BM>(At, A32 + (size_t)m0 * K + k0, K, tid);
        if constexpr (BB16)
            stage_b16<BN>(Bt, B16 + (size_t)n0 * K + k0, K, wave, lane);
        else
            stage_f32<BN>(Bt, B32 + (size_t)n0 * K + k0, K, tid);
        __syncthreads();  // compiler drains vmcnt(0) for global_load_lds here
#pragma unroll
        for (int kk = 0; kk < 64; kk += 32) {
            bf16x8 af[MF], bfr[NF];
#pragma unroll
            for (int f = 0; f < MF; ++f)
                af[f] = *(const bf16x8*)(At + (wm * (BM / 2) + f * 16 + fr) * 64 + kk + kg);
#pragma unroll
            for (int f = 0; f < NF; ++f)
                bfr[f] = *(const bf16x8*)(Bt + (wn * (BN / 2) + f * 16 + fr) * 64 + kk + kg);
#pragma unroll
            for (int mf = 0; mf < MF; ++mf)
#pragma unroll
                for (int nf = 0; nf < NF; ++nf)
                    acc[mf][nf] = MFMA16(af[mf], bfr[nf], acc[mf][nf]);
        }
        __syncthreads();
    }
    const int rb = (lane >> 4) << 2;
#pragma unroll
    for (int mf = 0; mf < MF; ++mf)
#pragma unroll
        for (int nf = 0; nf < NF; ++nf) {
            int n = n0 + wn * (BN / 2) + nf * 16 + fr;
            float bn = 0.f;
            if constexpr (OUTF32) bn = bias[n];
#pragma unroll
            for (int r = 0; r < 4; ++r) {
                int mm = m0 + wm * (BM / 2) + mf * 16 + rb + r;
                float v = acc[mf][nf][r];
                if constexpr (OUTF32)
                    Yf[(size_t)mm * ldy + n] = v + bn;
                else
                    Yb[(size_t)mm * ldy + n] = (bf16)(v * oscale);
            }
        }
}

// fp32 -> bf16 conversion pass (x inputs optional). 16M elems max, 4/thread.
__global__ __launch_bounds__(256) void cvt_all(const float* q, const float* k, const float* v,
                                               const float* Wq, const float* Wk,
                                               const float* Wv, const float* Wo,
                                               bf16* qc, bf16* kc, bf16* vc,
                                               bf16* Wqc, bf16* Wkc, bf16* Wvc, bf16* Woc,
                                               int doX) {
    const size_t NX = (size_t)Bsz * T * E;  // 4M
    const size_t NW = (size_t)E * E;        // 1M
    const size_t xtot = doX ? 3 * NX : 0;
    const size_t nwork = (xtot + 4 * NW) >> 2;
    for (size_t t = (size_t)blockIdx.x * 256 + threadIdx.x; t < nwork;
         t += (size_t)gridDim.x * 256) {
        size_t i = t << 2;
        const float* s;
        bf16* d;
        size_t off;
        if (i < xtot) {
            size_t w = i / NX;
            off = i - w * NX;
            s = w == 0 ? q : (w == 1 ? k : v);
            d = w == 0 ? qc : (w == 1 ? kc : vc);
        } else {
            size_t j = i - xtot;
            size_t w = j / NW;
            off = j - w * NW;
            s = w == 0 ? Wq : (w == 1 ? Wk : (w == 2 ? Wv : Wo));
            d = w == 0 ? Wqc : (w == 1 ? Wkc : (w == 2 ? Wvc : Woc));
        }
        const float4 x = *(const float4*)(s + off);
        bf16x4 y = {(bf16)x.x, (bf16)x.y, (bf16)x.z, (bf16)x.w};
        *(bf16x4*)(d + off) = y;
    }
}

// Fused Q/K/V^T projections: 768 blocks, XCD-swizzled, no dead blocks.
template <bool XB16, bool WB16>
__global__ __launch_bounds__(256) void qkv_proj(
    const float* q32, const float* k32, const float* v32,
    const bf16* q16, const bf16* k16, const bf16* v16,
    const float* Wq32, const float* Wk32, const float* Wv32,
    const bf16* Wq16, const bf16* Wk16, const bf16* Wv16,
    bf16* Qb, bf16* Kb, bf16* Vt) {
    __shared__ bf16 At[128 * 64];
    __shared__ bf16 Bt[128 * 64];
    const int bid = blockIdx.x;
    const int wid = (bid & 7) * 96 + (bid >> 3);  // 768 % 8 == 0: bijective
    if (wid < 512) {
        int s = wid >> 8;  // 0=Q (scaled by QSCALE), 1=K
        int t = wid & 255;
        int m0 = (t >> 3) * 128, n0 = (t & 7) * 128;
        gemm_body<XB16, WB16, 4, 4, false>(At, Bt,
                                           s ? k16 : q16, s ? k32 : q32,
                                           s ? Wk16 : Wq16, s ? Wk32 : Wq32,
                                           s ? Kb : Qb, nullptr, nullptr, m0, n0, E, E,
                                           s ? 1.0f : QSCALE);
    } else {
        int r = wid - 512;
        int b = r >> 7, rr = r & 127;
        int m0 = (rr >> 4) * 128, n0 = (rr & 15) * 128;
        gemm_body<WB16, XB16, 4, 4, false>(At, Bt,
                                           Wv16, Wv32,
                                           v16 + (size_t)b * T * E, v32 + (size_t)b * T * E,
                                           Vt + (size_t)b * E * T, nullptr, nullptr,
                                           m0, n0, E, T, 1.0f);
    }
}

// Output projection: 64x128 tiles -> 512 blocks (2/CU), fp32 out + bias.
template <bool WB16>
__global__ __launch_bounds__(256) void out_proj(const bf16* Xb, const bf16* W16,
                                                const float* W32, float* Y,
                                                const float* bias) {
    __shared__ bf16 At[64 * 64];
    __shared__ bf16 Bt[128 * 64];
    const int bid = blockIdx.x;
    const int wid = (bid & 7) * 64 + (bid >> 3);  // 512 % 8 == 0: bijective
    const int m0 = (wid >> 3) * 64, n0 = (wid & 7) * 128;
    gemm_body<true, WB16, 2, 4, true>(At, Bt, Xb, nullptr, W16, W32, nullptr, Y, bias,
                                      m0, n0, E, E, 1.0f);
}

// ---------------- Attention: swapped-QK^T 32x32, in-block split-K ----------
__device__ __forceinline__ uint pkbf(float a, float b) {
    uint16_t x = __builtin_bit_cast(uint16_t, (bf16)a);
    uint16_t y = __builtin_bit_cast(uint16_t, (bf16)b);
    return (uint)x | ((uint)y << 16);
}

// One 32-key x 32-q tile. kf holds this tile's K on entry; after QK^T it is
// refilled with the NEXT tile's K (nextkb>=0) -> load latency hides under
// softmax+PV. Scores arrive pre-scaled (QSCALE folded into Q): exp2 domain.
template <bool DIAG>
__device__ __forceinline__ void attn_tile(int kb, int nextkb, int l31, int hi,
                                          const bf16* __restrict__ Kp,
                                          const bf16* __restrict__ Vp,
                                          const bf16x8 (&qf)[4], bf16x8 (&kf)[4],
                                          f32x16& o0, f32x16& o1, float& m, float& l) {
    // V loads for this tile (consumed at PV ~500 cyc later)
    bf16x8 vf[2][2];
#pragma unroll
    for (int db = 0; db < 2; ++db)
#pragma unroll
        for (int c = 0; c < 2; ++c)
            vf[db][c] = *(const bf16x8*)(Vp + (size_t)(db * 32 + l31) * T + kb + c * 16 + hi * 8);

    // QK^T
    __builtin_amdgcn_s_setprio(1);
    f32x16 s = {};
#pragma unroll
    for (int t = 0; t < 4; ++t) s = MFMA32(kf[t], qf[t], s);
    __builtin_amdgcn_s_setprio(0);

    // kf registers are dead now: prefetch next tile's K into them
    if (nextkb >= 0) {
#pragma unroll
        for (int t = 0; t < 4; ++t)
            kf[t] = *(const bf16x8*)(Kp + (size_t)(nextkb + l31) * E + t * 16 + hi * 8);
    }

    float sv[16];
#pragma unroll
    for (int r = 0; r < 16; ++r) {
        float x = s[r];
        if constexpr (DIAG) {
            int key = (r & 3) + 8 * (r >> 2) + 4 * hi;
            if (key > l31) x = -1e30f;
        }
        sv[r] = x;
    }
    float pm = sv[0];
#pragma unroll
    for (int r = 1; r < 16; ++r) pm = fmaxf(pm, sv[r]);
    pm = fmaxf(pm, __shfl_xor(pm, 32, 64));  // cross-half max

    if (!__all(pm - m <= 11.5f)) {  // deferred rescale (T13), 8*log2e
        float mn = fmaxf(m, pm);
        float al = exp2fast(m - mn);
        m = mn;
        l *= al;
#pragma unroll
        for (int r = 0; r < 16; ++r) {
            int qr = (r & 3) + 8 * (r >> 2) + 4 * hi;
            float aq = __shfl(al, qr, 64);
            o0[r] *= aq;
            o1[r] *= aq;
        }
    }
    float p[16];
    float ps = 0.f;
#pragma unroll
    for (int r = 0; r < 16; ++r) {
        p[r] = exp2fast(sv[r] - m);
        ps += p[r];
    }
    l += ps + __shfl_xor(ps, 32, 64);  // cross-half sum

    // P -> PV A-fragments (round-4 verified shfl_xor routing)
    __builtin_amdgcn_s_setprio(1);
#pragma unroll
    for (int cc = 0; cc < 2; ++cc) {
        int bse = cc * 8;
        uint x0 = pkbf(p[bse + 0], p[bse + 1]);
        uint x1 = pkbf(p[bse + 2], p[bse + 3]);
        uint y0 = pkbf(p[bse + 4], p[bse + 5]);
        uint y1 = pkbf(p[bse + 6], p[bse + 7]);
        uint sx0 = __shfl_xor(x0, 32, 64), sx1 = __shfl_xor(x1, 32, 64);
        uint sy0 = __shfl_xor(y0, 32, 64), sy1 = __shfl_xor(y1, 32, 64);
        u32x4 wv;
        wv.x = hi ? sy0 : x0;
        wv.y = hi ? sy1 : x1;
        wv.z = hi ? y0 : sx0;
        wv.w = hi ? y1 : sx1;
        bf16x8 pa = __builtin_bit_cast(bf16x8, wv);
        o0 = MFMA32(pa, vf[0][cc], o0);
        o1 = MFMA32(pa, vf[1][cc], o1);
    }
    __builtin_amdgcn_s_setprio(0);
}

// 4 waves/block, in-block split-K. Balanced pairing: job i does q-tile 63-i
// then q-tile i -> every block executes exactly 65 tile-iters (no tail).
__global__ __launch_bounds__(256) void attn_fwd(const bf16* __restrict__ Q,
                                                const bf16* __restrict__ K,
                                                const bf16* __restrict__ Vt,
                                                bf16* __restrict__ O) {
    __shared__ float oS[4][64 * 18];  // stride 18: 2-way-max bank conflicts
    __shared__ float mS[4][32], lS[4][32];

    const int g = blockIdx.x;
    const int xcd = g & 7, j = g >> 3;  // 1024 % 8 == 0: bijective
    const int hb = xcd * 4 + (j >> 5);  // 4 heads per XCD (L2 locality)
    const int job = j & 31;             // 0..31
    const int h = hb & 15, b = hb >> 4;

    const int tid = threadIdx.x, lane = tid & 63, w = tid >> 6;
    const int l31 = lane & 31, hi = lane >> 5;

    const bf16* Qp = Q + (size_t)b * T * E + h * Dh;
    const bf16* Kp = K + (size_t)b * T * E + h * Dh;
    const bf16* Vp = Vt + ((size_t)b * E + h * Dh) * T;
    bf16* Op = O + (size_t)b * T * E + h * Dh;

#pragma unroll 1
    for (int ph = 0; ph < 2; ++ph) {
        const int qt = ph ? job : 63 - job;  // heavy phase first
        const int q0 = qt * 32;

        bf16x8 qf[4];
#pragma unroll
        for (int t = 0; t < 4; ++t)
            qf[t] = *(const bf16x8*)(Qp + (size_t)(q0 + l31) * E + t * 16 + hi * 8);

        f32x16 o0 = {}, o1 = {};
        float m = -1e30f, l = 0.f;

        const bool dg = ((qt & 3) == w);
        bf16x8 kf[4];
        const int first = (w < qt) ? w * 32 : (dg ? q0 : -1);
        if (first >= 0) {
#pragma unroll
            for (int t = 0; t < 4; ++t)
                kf[t] = *(const bf16x8*)(Kp + (size_t)(first + l31) * E + t * 16 + hi * 8);
        }
        for (int kt = w; kt < qt; kt += 4) {
            const int kn = kt + 4;
            const int nextkb = (kn < qt) ? kn * 32 : (dg ? q0 : -1);
            attn_tile<false>(kt * 32, nextkb, l31, hi, Kp, Vp, qf, kf, o0, o1, m, l);
        }
        if (dg)
            attn_tile<true>(q0, -1, l31, hi, Kp, Vp, qf, kf, o0, o1, m, l);

        // ---- in-block combine of 4 split-K partials ----
        __syncthreads();  // phase boundary: prev combine's mS/lS/oS reads done
        if (lane < 32) {
            mS[w][l31] = m;
            lS[w][l31] = l;
        }
#pragma unroll
        for (int half = 0; half < 2; ++half) {
            const f32x16 oo = half ? o1 : o0;  // static after unroll
            __syncthreads();                   // oS reuse guard (and m/l visibility)
            float* row = oS[w] + lane * 18;
#pragma unroll
            for (int jj = 0; jj < 8; ++jj)
                *(float2*)(row + 2 * jj) = make_float2(oo[2 * jj], oo[2 * jj + 1]);
            __syncthreads();
            // wave w combines r = 4w..4w+3 for all 64 lanes; q = (r&3)+8*(r>>2)+4*hi
#pragma unroll
            for (int t = 0; t < 4; ++t) {
                const int q = t + 8 * w + 4 * hi;
                const int r = 4 * w + t;
                float m0v = mS[0][q], m1 = mS[1][q], m2 = mS[2][q], m3 = mS[3][q];
                float M = fmaxf(fmaxf(m0v, m1), fmaxf(m2, m3));
                float w0 = exp2fast(m0v - M), w1 = exp2fast(m1 - M);
                float w2 = exp2fast(m2 - M), w3 = exp2fast(m3 - M);
                float L = lS[0][q] * w0 + lS[1][q] * w1 + lS[2][q] * w2 + lS[3][q] * w3;
                float val = oS[0][lane * 18 + r] * w0 + oS[1][lane * 18 + r] * w1 +
                            oS[2][lane * 18 + r] * w2 + oS[3][lane * 18 + r] * w3;
                float inv = __builtin_amdgcn_rcpf(L);
                Op[(size_t)(q0 + q) * E + half * 32 + l31] = (bf16)(val * inv);
            }
        }
    }
}

extern "C" void kernel_launch(void* const* d_in, const int* in_sizes, int n_in,
                              void* d_out, int out_size, void* d_ws, size_t ws_size,
                              hipStream_t stream) {
    const float* k_in = (const float*)d_in[0];
    const float* q_in = (const float*)d_in[1];
    const float* v_in = (const float*)d_in[2];
    const float* Wk = (const float*)d_in[3];
    const float* Wq = (const float*)d_in[4];
    const float* Wv = (const float*)d_in[5];
    const float* Wo = (const float*)d_in[6];
    const float* bo = (const float*)d_in[7];
    float* out = (float*)d_out;

    const size_t NE = (size_t)Bsz * T * E;  // 4M
    const size_t NW = (size_t)E * E;        // 1M
    bf16* ws = (bf16*)d_ws;
    bf16* Qb = ws;            // [B*T][E]  (pre-scaled by QSCALE)
    bf16* Kb = ws + NE;       // [B*T][E]
    bf16* Vt = ws + 2 * NE;   // [B][E][T]
    bf16* Ab = ws + 3 * NE;   // attn out; also aliases qc (dead by then)
    bf16* Wqc = ws + 4 * NE;
    bf16* Wkc = Wqc + NW;
    bf16* Wvc = Wkc + NW;
    bf16* Woc = Wvc + NW;
    bf16* qc = Ab;            // alias: qc dead after qkv_proj, Ab written after
    bf16* kc = ws + 4 * NE + 4 * NW;
    bf16* vc = kc + NE;

    const bool planA = ws_size >= (4 * NE + 4 * NW + 2 * NE) * sizeof(bf16);  // 56 MB
    const bool planB = ws_size >= (4 * NE + 4 * NW) * sizeof(bf16);           // 40 MB

    if (planA) {
        cvt_all<<<2048, 256, 0, stream>>>(q_in, k_in, v_in, Wq, Wk, Wv, Wo,
                                          qc, kc, vc, Wqc, Wkc, Wvc, Woc, 1);
        qkv_proj<true, true><<<768, 256, 0, stream>>>(
            nullptr, nullptr, nullptr, qc, kc, vc,
            nullptr, nullptr, nullptr, Wqc, Wkc, Wvc, Qb, Kb, Vt);
    } else if (planB) {
        cvt_all<<<2048, 256, 0, stream>>>(q_in, k_in, v_in, Wq, Wk, Wv, Wo,
                                          nullptr, nullptr, nullptr, Wqc, Wkc, Wvc, Woc, 0);
        qkv_proj<false, true><<<768, 256, 0, stream>>>(
            q_in, k_in, v_in, nullptr, nullptr, nullptr,
            nullptr, nullptr, nullptr, Wqc, Wkc, Wvc, Qb, Kb, Vt);
    } else {
        qkv_proj<false, false><<<768, 256, 0, stream>>>(
            q_in, k_in, v_in, nullptr, nullptr, nullptr,
            Wq, Wk, Wv, nullptr, nullptr, nullptr, Qb, Kb, Vt);
    }

    attn_fwd<<<dim3(1024), 256, 0, stream>>>(Qb, Kb, Vt, Ab);

    if (planB)
        out_proj<true><<<512, 256, 0, stream>>>(Ab, Woc, nullptr, out, bo);
    else
        out_proj<false><<<512, 256, 0, stream>>>(Ab, nullptr, Wo, out, bo);
}

// Round 9
// 158.113 us; speedup vs baseline: 1.9526x; 1.0076x over previous
//
#include <hip/hip_runtime.h>
#include <stdint.h>

typedef __bf16 bf16;
typedef bf16 bf16x8 __attribute__((ext_vector_type(8)));
typedef bf16 bf16x4 __attribute__((ext_vector_type(4)));
typedef float f32x4 __attribute__((ext_vector_type(4)));
typedef float f32x16 __attribute__((ext_vector_type(16)));
typedef unsigned int uint;
typedef uint u32x4 __attribute__((ext_vector_type(4)));

#define MFMA16(a, b, c) __builtin_amdgcn_mfma_f32_16x16x32_bf16(a, b, c, 0, 0, 0)
#define MFMA32(a, b, c) __builtin_amdgcn_mfma_f32_32x32x16_bf16(a, b, c, 0, 0, 0)

static constexpr int Bsz = 2, T = 2048, E = 1024, H = 16, Dh = 64;
// softmax scale folded into Q at projection; exp2-domain: 1/sqrt(64) * log2(e)
static constexpr float QSCALE = 0.125f * 1.44269504088896f;

__device__ __forceinline__ float exp2fast(float x) {
#if __has_builtin(__builtin_amdgcn_exp2f)
    return __builtin_amdgcn_exp2f(x);
#else
    return exp2f(x);
#endif
}

// async global->LDS, 16B per lane. LDS dest must be wave-uniform base (HW adds lane*16).
__device__ __forceinline__ void gll16(const bf16* g, bf16* l) {
    __builtin_amdgcn_global_load_lds((const __attribute__((address_space(1))) uint*)g,
                                     (__attribute__((address_space(3))) uint*)l, 16, 0, 0);
}

// ---- staging: ROWS x 64 bf16 tile into linear LDS ([row][64], 128B rows) ----
template <int ROWS>
__device__ __forceinline__ void stage_b16(bf16* lds, const bf16* g, int ldg, int wave, int lane) {
#pragma unroll
    for (int i = 0; i < ROWS / 32; ++i) {
        const int row = wave * (ROWS / 4) + i * 8;  // wave-uniform
        gll16(g + (size_t)(row + (lane >> 3)) * ldg + (lane & 7) * 8, lds + row * 64);
    }
}
template <int ROWS>
__device__ __forceinline__ void stage_f32(bf16* lds, const float* g, int ldg, int tid) {
#pragma unroll
    for (int i = 0; i < ROWS / 16; ++i) {
        int gg = tid + i * 256;
        int row = gg >> 4, c4 = (gg & 15) << 2;
        const float4 v = *(const float4*)(g + (size_t)row * ldg + c4);
        bf16x4 bv = {(bf16)v.x, (bf16)v.y, (bf16)v.z, (bf16)v.w};
        *(bf16x4*)(lds + row * 64 + c4) = bv;
    }
}

// ------------- GEMM body: Y[M,N] = A[M,K] @ B[N,K]^T (+bias) ---------------
template <bool AB16, bool BB16, int MF, int NF, bool OUTF32>
__device__ __forceinline__ void gemm_body(bf16* At, bf16* Bt,
                                          const bf16* A16, const float* A32,
                                          const bf16* B16, const float* B32,
                                          bf16* Yb, float* Yf, const float* bias,
                                          int m0, int n0, int K, int ldy, float oscale) {
    constexpr int BM = MF * 32, BN = NF * 32;
    const int tid = threadIdx.x, lane = tid & 63, wave = tid >> 6;
    const int wm = wave >> 1, wn = wave & 1;
    const int fr = lane & 15, kg = (lane >> 4) << 3;

    f32x4 acc[MF][NF] = {};

    for (int k0 = 0; k0 < K; k0 += 64) {
        if constexpr (AB16)
            stage_b16<BM>(At, A16 + (size_t)m0 * K + k0, K, wave, lane);
        else
            stage_f32<BM>(At, A32 + (size_t)m0 * K + k0, K, tid);
        if constexpr (BB16)
            stage_b16<BN>(Bt, B16 + (size_t)n0 * K + k0, K, wave, lane);
        else
            stage_f32<BN>(Bt, B32 + (size_t)n0 * K + k0, K, tid);
        __syncthreads();  // compiler drains vmcnt(0) for global_load_lds here
#pragma unroll
        for (int kk = 0; kk < 64; kk += 32) {
            bf16x8 af[MF], bfr[NF];
#pragma unroll
            for (int f = 0; f < MF; ++f)
                af[f] = *(const bf16x8*)(At + (wm * (BM / 2) + f * 16 + fr) * 64 + kk + kg);
#pragma unroll
            for (int f = 0; f < NF; ++f)
                bfr[f] = *(const bf16x8*)(Bt + (wn * (BN / 2) + f * 16 + fr) * 64 + kk + kg);
#pragma unroll
            for (int mf = 0; mf < MF; ++mf)
#pragma unroll
                for (int nf = 0; nf < NF; ++nf)
                    acc[mf][nf] = MFMA16(af[mf], bfr[nf], acc[mf][nf]);
        }
        __syncthreads();
    }
    const int rb = (lane >> 4) << 2;
#pragma unroll
    for (int mf = 0; mf < MF; ++mf)
#pragma unroll
        for (int nf = 0; nf < NF; ++nf) {
            int n = n0 + wn * (BN / 2) + nf * 16 + fr;
            float bn = 0.f;
            if constexpr (OUTF32) bn = bias[n];
#pragma unroll
            for (int r = 0; r < 4; ++r) {
                int mm = m0 + wm * (BM / 2) + mf * 16 + rb + r;
                float v = acc[mf][nf][r];
                if constexpr (OUTF32)
                    Yf[(size_t)mm * ldy + n] = v + bn;
                else
                    Yb[(size_t)mm * ldy + n] = (bf16)(v * oscale);
            }
        }
}

// fp32 -> bf16 conversion pass (x inputs optional). 16M elems max, 4/thread.
__global__ __launch_bounds__(256) void cvt_all(const float* q, const float* k, const float* v,
                                               const float* Wq, const float* Wk,
                                               const float* Wv, const float* Wo,
                                               bf16* qc, bf16* kc, bf16* vc,
                                               bf16* Wqc, bf16* Wkc, bf16* Wvc, bf16* Woc,
                                               int doX) {
    const size_t NX = (size_t)Bsz * T * E;  // 4M
    const size_t NW = (size_t)E * E;        // 1M
    const size_t xtot = doX ? 3 * NX : 0;
    const size_t nwork = (xtot + 4 * NW) >> 2;
    for (size_t t = (size_t)blockIdx.x * 256 + threadIdx.x; t < nwork;
         t += (size_t)gridDim.x * 256) {
        size_t i = t << 2;
        const float* s;
        bf16* d;
        size_t off;
        if (i < xtot) {
            size_t w = i / NX;
            off = i - w * NX;
            s = w == 0 ? q : (w == 1 ? k : v);
            d = w == 0 ? qc : (w == 1 ? kc : vc);
        } else {
            size_t j = i - xtot;
            size_t w = j / NW;
            off = j - w * NW;
            s = w == 0 ? Wq : (w == 1 ? Wk : (w == 2 ? Wv : Wo));
            d = w == 0 ? Wqc : (w == 1 ? Wkc : (w == 2 ? Wvc : Woc));
        }
        const float4 x = *(const float4*)(s + off);
        bf16x4 y = {(bf16)x.x, (bf16)x.y, (bf16)x.z, (bf16)x.w};
        *(bf16x4*)(d + off) = y;
    }
}

// Fused Q/K/V^T projections: 768 blocks, XCD-swizzled, no dead blocks.
template <bool XB16, bool WB16>
__global__ __launch_bounds__(256) void qkv_proj(
    const float* q32, const float* k32, const float* v32,
    const bf16* q16, const bf16* k16, const bf16* v16,
    const float* Wq32, const float* Wk32, const float* Wv32,
    const bf16* Wq16, const bf16* Wk16, const bf16* Wv16,
    bf16* Qb, bf16* Kb, bf16* Vt) {
    __shared__ bf16 At[128 * 64];
    __shared__ bf16 Bt[128 * 64];
    const int bid = blockIdx.x;
    const int wid = (bid & 7) * 96 + (bid >> 3);  // 768 % 8 == 0: bijective
    if (wid < 512) {
        int s = wid >> 8;  // 0=Q (scaled by QSCALE), 1=K
        int t = wid & 255;
        int m0 = (t >> 3) * 128, n0 = (t & 7) * 128;
        gemm_body<XB16, WB16, 4, 4, false>(At, Bt,
                                           s ? k16 : q16, s ? k32 : q32,
                                           s ? Wk16 : Wq16, s ? Wk32 : Wq32,
                                           s ? Kb : Qb, nullptr, nullptr, m0, n0, E, E,
                                           s ? 1.0f : QSCALE);
    } else {
        int r = wid - 512;
        int b = r >> 7, rr = r & 127;
        int m0 = (rr >> 4) * 128, n0 = (rr & 15) * 128;
        gemm_body<WB16, XB16, 4, 4, false>(At, Bt,
                                           Wv16, Wv32,
                                           v16 + (size_t)b * T * E, v32 + (size_t)b * T * E,
                                           Vt + (size_t)b * E * T, nullptr, nullptr,
                                           m0, n0, E, T, 1.0f);
    }
}

// Output projection: 64x128 tiles -> 512 blocks (2/CU), fp32 out + bias.
template <bool WB16>
__global__ __launch_bounds__(256) void out_proj(const bf16* Xb, const bf16* W16,
                                                const float* W32, float* Y,
                                                const float* bias) {
    __shared__ bf16 At[64 * 64];
    __shared__ bf16 Bt[128 * 64];
    const int bid = blockIdx.x;
    const int wid = (bid & 7) * 64 + (bid >> 3);  // 512 % 8 == 0: bijective
    const int m0 = (wid >> 3) * 64, n0 = (wid & 7) * 128;
    gemm_body<true, WB16, 2, 4, true>(At, Bt, Xb, nullptr, W16, W32, nullptr, Y, bias,
                                      m0, n0, E, E, 1.0f);
}

// ---------------- Attention: swapped-QK^T 32x32, in-block split-K ----------
__device__ __forceinline__ uint pkbf(float a, float b) {
    uint16_t x = __builtin_bit_cast(uint16_t, (bf16)a);
    uint16_t y = __builtin_bit_cast(uint16_t, (bf16)b);
    return (uint)x | ((uint)y << 16);
}

// One 32-key x 32-q tile. kf holds this tile's K on entry; after QK^T it is
// refilled with the NEXT tile's K (nextkb>=0) -> load latency hides under
// softmax+PV. Scores arrive pre-scaled (QSCALE folded into Q): exp2 domain.
template <bool DIAG>
__device__ __forceinline__ void attn_tile(int kb, int nextkb, int l31, int hi,
                                          const bf16* __restrict__ Kp,
                                          const bf16* __restrict__ Vp,
                                          const bf16x8 (&qf)[4], bf16x8 (&kf)[4],
                                          f32x16& o0, f32x16& o1, float& m, float& l) {
    // V loads for this tile (consumed at PV ~500 cyc later)
    bf16x8 vf[2][2];
#pragma unroll
    for (int db = 0; db < 2; ++db)
#pragma unroll
        for (int c = 0; c < 2; ++c)
            vf[db][c] = *(const bf16x8*)(Vp + (size_t)(db * 32 + l31) * T + kb + c * 16 + hi * 8);

    // QK^T
    __builtin_amdgcn_s_setprio(1);
    f32x16 s = {};
#pragma unroll
    for (int t = 0; t < 4; ++t) s = MFMA32(kf[t], qf[t], s);
    __builtin_amdgcn_s_setprio(0);

    // kf registers are dead now: prefetch next tile's K into them
    if (nextkb >= 0) {
#pragma unroll
        for (int t = 0; t < 4; ++t)
            kf[t] = *(const bf16x8*)(Kp + (size_t)(nextkb + l31) * E + t * 16 + hi * 8);
    }

    // causal mask in place (no copy)
    if constexpr (DIAG) {
#pragma unroll
        for (int r = 0; r < 16; ++r) {
            int key = (r & 3) + 8 * (r >> 2) + 4 * hi;
            if (key > l31) s[r] = -1e30f;
        }
    }
    // row-max: depth-4 tree + cross-half exchange
    float t8[8];
#pragma unroll
    for (int r = 0; r < 8; ++r) t8[r] = fmaxf(s[r], s[r + 8]);
#pragma unroll
    for (int r = 0; r < 4; ++r) t8[r] = fmaxf(t8[r], t8[r + 4]);
    float pm = fmaxf(fmaxf(t8[0], t8[1]), fmaxf(t8[2], t8[3]));
    pm = fmaxf(pm, __shfl_xor(pm, 32, 64));

    if (!__all(pm - m <= 11.5f)) {  // deferred rescale (T13), 8*log2e
        float mn = fmaxf(m, pm);
        float al = exp2fast(m - mn);
        m = mn;
        l *= al;
#pragma unroll
        for (int r = 0; r < 16; ++r) {
            int qr = (r & 3) + 8 * (r >> 2) + 4 * hi;
            float aq = __shfl(al, qr, 64);
            o0[r] *= aq;
            o1[r] *= aq;
        }
    }
    float p[16];
#pragma unroll
    for (int r = 0; r < 16; ++r) p[r] = exp2fast(s[r] - m);
    // row-sum: depth-4 tree + cross-half exchange
    float u8[8];
#pragma unroll
    for (int r = 0; r < 8; ++r) u8[r] = p[r] + p[r + 8];
#pragma unroll
    for (int r = 0; r < 4; ++r) u8[r] = u8[r] + u8[r + 4];
    float ps = (u8[0] + u8[1]) + (u8[2] + u8[3]);
    l += ps + __shfl_xor(ps, 32, 64);

    // P -> PV A-fragments (round-4 verified shfl_xor routing)
    __builtin_amdgcn_s_setprio(1);
#pragma unroll
    for (int cc = 0; cc < 2; ++cc) {
        int bse = cc * 8;
        uint x0 = pkbf(p[bse + 0], p[bse + 1]);
        uint x1 = pkbf(p[bse + 2], p[bse + 3]);
        uint y0 = pkbf(p[bse + 4], p[bse + 5]);
        uint y1 = pkbf(p[bse + 6], p[bse + 7]);
        uint sx0 = __shfl_xor(x0, 32, 64), sx1 = __shfl_xor(x1, 32, 64);
        uint sy0 = __shfl_xor(y0, 32, 64), sy1 = __shfl_xor(y1, 32, 64);
        u32x4 wv;
        wv.x = hi ? sy0 : x0;
        wv.y = hi ? sy1 : x1;
        wv.z = hi ? y0 : sx0;
        wv.w = hi ? y1 : sx1;
        bf16x8 pa = __builtin_bit_cast(bf16x8, wv);
        o0 = MFMA32(pa, vf[0][cc], o0);
        o1 = MFMA32(pa, vf[1][cc], o1);
    }
    __builtin_amdgcn_s_setprio(0);
}

// 4 waves/block, in-block split-K. Balanced pairing: job i does q-tile 63-i
// then q-tile i -> every block executes exactly 65 tile-iters (no tail).
// __launch_bounds__(256,3): cap unified VGPR+AGPR at ~170 -> 3 waves/SIMD
// (round-8 counters showed the 2-waves/SIMD register ceiling was binding).
__global__ __launch_bounds__(256, 3) void attn_fwd(const bf16* __restrict__ Q,
                                                   const bf16* __restrict__ K,
                                                   const bf16* __restrict__ Vt,
                                                   bf16* __restrict__ O) {
    __shared__ float oS[4][64 * 18];  // stride 18: 2-way-max bank conflicts
    __shared__ float mS[4][32], lS[4][32];

    const int g = blockIdx.x;
    const int xcd = g & 7, j = g >> 3;  // 1024 % 8 == 0: bijective
    const int hb = xcd * 4 + (j >> 5);  // 4 heads per XCD (L2 locality)
    const int job = j & 31;             // 0..31
    const int h = hb & 15, b = hb >> 4;

    const int tid = threadIdx.x, lane = tid & 63, w = tid >> 6;
    const int l31 = lane & 31, hi = lane >> 5;

    const bf16* Qp = Q + (size_t)b * T * E + h * Dh;
    const bf16* Kp = K + (size_t)b * T * E + h * Dh;
    const bf16* Vp = Vt + ((size_t)b * E + h * Dh) * T;
    bf16* Op = O + (size_t)b * T * E + h * Dh;

#pragma unroll 1
    for (int ph = 0; ph < 2; ++ph) {
        const int qt = ph ? job : 63 - job;  // heavy phase first
        const int q0 = qt * 32;

        bf16x8 qf[4];
#pragma unroll
        for (int t = 0; t < 4; ++t)
            qf[t] = *(const bf16x8*)(Qp + (size_t)(q0 + l31) * E + t * 16 + hi * 8);

        f32x16 o0 = {}, o1 = {};
        float m = -1e30f, l = 0.f;

        const bool dg = ((qt & 3) == w);
        bf16x8 kf[4];
        const int first = (w < qt) ? w * 32 : (dg ? q0 : -1);
        if (first >= 0) {
#pragma unroll
            for (int t = 0; t < 4; ++t)
                kf[t] = *(const bf16x8*)(Kp + (size_t)(first + l31) * E + t * 16 + hi * 8);
        }
        for (int kt = w; kt < qt; kt += 4) {
            const int kn = kt + 4;
            const int nextkb = (kn < qt) ? kn * 32 : (dg ? q0 : -1);
            attn_tile<false>(kt * 32, nextkb, l31, hi, Kp, Vp, qf, kf, o0, o1, m, l);
        }
        if (dg)
            attn_tile<true>(q0, -1, l31, hi, Kp, Vp, qf, kf, o0, o1, m, l);

        // ---- in-block combine of 4 split-K partials ----
        __syncthreads();  // phase boundary: prev combine's mS/lS/oS reads done
        if (lane < 32) {
            mS[w][l31] = m;
            lS[w][l31] = l;
        }
#pragma unroll
        for (int half = 0; half < 2; ++half) {
            const f32x16 oo = half ? o1 : o0;  // static after unroll
            __syncthreads();                   // oS reuse guard (and m/l visibility)
            float* row = oS[w] + lane * 18;
#pragma unroll
            for (int jj = 0; jj < 8; ++jj)
                *(float2*)(row + 2 * jj) = make_float2(oo[2 * jj], oo[2 * jj + 1]);
            __syncthreads();
            // wave w combines r = 4w..4w+3 for all 64 lanes; q = (r&3)+8*(r>>2)+4*hi
#pragma unroll
            for (int t = 0; t < 4; ++t) {
                const int q = t + 8 * w + 4 * hi;
                const int r = 4 * w + t;
                float m0v = mS[0][q], m1 = mS[1][q], m2 = mS[2][q], m3 = mS[3][q];
                float M = fmaxf(fmaxf(m0v, m1), fmaxf(m2, m3));
                float w0 = exp2fast(m0v - M), w1 = exp2fast(m1 - M);
                float w2 = exp2fast(m2 - M), w3 = exp2fast(m3 - M);
                float L = lS[0][q] * w0 + lS[1][q] * w1 + lS[2][q] * w2 + lS[3][q] * w3;
                float val = oS[0][lane * 18 + r] * w0 + oS[1][lane * 18 + r] * w1 +
                            oS[2][lane * 18 + r] * w2 + oS[3][lane * 18 + r] * w3;
                float inv = __builtin_amdgcn_rcpf(L);
                Op[(size_t)(q0 + q) * E + half * 32 + l31] = (bf16)(val * inv);
            }
        }
    }
}

extern "C" void kernel_launch(void* const* d_in, const int* in_sizes, int n_in,
                              void* d_out, int out_size, void* d_ws, size_t ws_size,
                              hipStream_t stream) {
    const float* k_in = (const float*)d_in[0];
    const float* q_in = (const float*)d_in[1];
    const float* v_in = (const float*)d_in[2];
    const float* Wk = (const float*)d_in[3];
    const float* Wq = (const float*)d_in[4];
    const float* Wv = (const float*)d_in[5];
    const float* Wo = (const float*)d_in[6];
    const float* bo = (const float*)d_in[7];
    float* out = (float*)d_out;

    const size_t NE = (size_t)Bsz * T * E;  // 4M
    const size_t NW = (size_t)E * E;        // 1M
    bf16* ws = (bf16*)d_ws;
    bf16* Qb = ws;            // [B*T][E]  (pre-scaled by QSCALE)
    bf16* Kb = ws + NE;       // [B*T][E]
    bf16* Vt = ws + 2 * NE;   // [B][E][T]
    bf16* Ab = ws + 3 * NE;   // attn out; also aliases qc (dead by then)
    bf16* Wqc = ws + 4 * NE;
    bf16* Wkc = Wqc + NW;
    bf16* Wvc = Wkc + NW;
    bf16* Woc = Wvc + NW;
    bf16* qc = Ab;            // alias: qc dead after qkv_proj, Ab written after
    bf16* kc = ws + 4 * NE + 4 * NW;
    bf16* vc = kc + NE;

    const bool planA = ws_size >= (4 * NE + 4 * NW + 2 * NE) * sizeof(bf16);  // 56 MB
    const bool planB = ws_size >= (4 * NE + 4 * NW) * sizeof(bf16);           // 40 MB

    if (planA) {
        cvt_all<<<2048, 256, 0, stream>>>(q_in, k_in, v_in, Wq, Wk, Wv, Wo,
                                          qc, kc, vc, Wqc, Wkc, Wvc, Woc, 1);
        qkv_proj<true, true><<<768, 256, 0, stream>>>(
            nullptr, nullptr, nullptr, qc, kc, vc,
            nullptr, nullptr, nullptr, Wqc, Wkc, Wvc, Qb, Kb, Vt);
    } else if (planB) {
        cvt_all<<<2048, 256, 0, stream>>>(q_in, k_in, v_in, Wq, Wk, Wv, Wo,
                                          nullptr, nullptr, nullptr, Wqc, Wkc, Wvc, Woc, 0);
        qkv_proj<false, true><<<768, 256, 0, stream>>>(
            q_in, k_in, v_in, nullptr, nullptr, nullptr,
            nullptr, nullptr, nullptr, Wqc, Wkc, Wvc, Qb, Kb, Vt);
    } else {
        qkv_proj<false, false><<<768, 256, 0, stream>>>(
            q_in, k_in, v_in, nullptr, nullptr, nullptr,
            Wq, Wk, Wv, nullptr, nullptr, nullptr, Qb, Kb, Vt);
    }

    attn_fwd<<<dim3(1024), 256, 0, stream>>>(Qb, Kb, Vt, Ab);

    if (planB)
        out_proj<true><<<512, 256, 0, stream>>>(Ab, Woc, nullptr, out, bo);
    else
        out_proj<false><<<512, 256, 0, stream>>>(Ab, nullptr, Wo, out, bo);
}

// Round 10
// 156.084 us; speedup vs baseline: 1.9780x; 1.0130x over previous
//
#include <hip/hip_runtime.h>
#include <stdint.h>

typedef __bf16 bf16;
typedef bf16 bf16x8 __attribute__((ext_vector_type(8)));
typedef bf16 bf16x4 __attribute__((ext_vector_type(4)));
typedef float f32x4 __attribute__((ext_vector_type(4)));
typedef float f32x16 __attribute__((ext_vector_type(16)));
typedef unsigned int uint;
typedef uint u32x4 __attribute__((ext_vector_type(4)));

#define MFMA16(a, b, c) __builtin_amdgcn_mfma_f32_16x16x32_bf16(a, b, c, 0, 0, 0)
#define MFMA32(a, b, c) __builtin_amdgcn_mfma_f32_32x32x16_bf16(a, b, c, 0, 0, 0)

static constexpr int Bsz = 2, T = 2048, E = 1024, H = 16, Dh = 64;
// softmax scale folded into Q at projection; exp2-domain: 1/sqrt(64) * log2(e)
static constexpr float QSCALE = 0.125f * 1.44269504088896f;

__device__ __forceinline__ float exp2fast(float x) {
#if __has_builtin(__builtin_amdgcn_exp2f)
    return __builtin_amdgcn_exp2f(x);
#else
    return exp2f(x);
#endif
}

// async global->LDS, 16B per lane. LDS dest must be wave-uniform base (HW adds lane*16).
__device__ __forceinline__ void gll16(const bf16* g, bf16* l) {
    __builtin_amdgcn_global_load_lds((const __attribute__((address_space(1))) uint*)g,
                                     (__attribute__((address_space(3))) uint*)l, 16, 0, 0);
}

// ---- staging: ROWS x 64 bf16 tile into linear LDS ([row][64], 128B rows) ----
template <int ROWS>
__device__ __forceinline__ void stage_b16(bf16* lds, const bf16* g, int ldg, int wave, int lane) {
#pragma unroll
    for (int i = 0; i < ROWS / 32; ++i) {
        const int row = wave * (ROWS / 4) + i * 8;  // wave-uniform
        gll16(g + (size_t)(row + (lane >> 3)) * ldg + (lane & 7) * 8, lds + row * 64);
    }
}
template <int ROWS>
__device__ __forceinline__ void stage_f32(bf16* lds, const float* g, int ldg, int tid) {
#pragma unroll
    for (int i = 0; i < ROWS / 16; ++i) {
        int gg = tid + i * 256;
        int row = gg >> 4, c4 = (gg & 15) << 2;
        const float4 v = *(const float4*)(g + (size_t)row * ldg + c4);
        bf16x4 bv = {(bf16)v.x, (bf16)v.y, (bf16)v.z, (bf16)v.w};
        *(bf16x4*)(lds + row * 64 + c4) = bv;
    }
}

// ------------- GEMM body: Y[M,N] = A[M,K] @ B[N,K]^T (+bias) ---------------
template <bool AB16, bool BB16, int MF, int NF, bool OUTF32>
__device__ __forceinline__ void gemm_body(bf16* At, bf16* Bt,
                                          const bf16* A16, const float* A32,
                                          const bf16* B16, const float* B32,
                                          bf16* Yb, float* Yf, const float* bias,
                                          int m0, int n0, int K, int ldy, float oscale) {
    constexpr int BM = MF * 32, BN = NF * 32;
    const int tid = threadIdx.x, lane = tid & 63, wave = tid >> 6;
    const int wm = wave >> 1, wn = wave & 1;
    const int fr = lane & 15, kg = (lane >> 4) << 3;

    f32x4 acc[MF][NF] = {};

    for (int k0 = 0; k0 < K; k0 += 64) {
        if constexpr (AB16)
            stage_b16<BM>(At, A16 + (size_t)m0 * K + k0, K, wave, lane);
        else
            stage_f32<BM>(At, A32 + (size_t)m0 * K + k0, K, tid);
        if constexpr (BB16)
            stage_b16<BN>(Bt, B16 + (size_t)n0 * K + k0, K, wave, lane);
        else
            stage_f32<BN>(Bt, B32 + (size_t)n0 * K + k0, K, tid);
        __syncthreads();  // compiler drains vmcnt(0) for global_load_lds here
#pragma unroll
        for (int kk = 0; kk < 64; kk += 32) {
            bf16x8 af[MF], bfr[NF];
#pragma unroll
            for (int f = 0; f < MF; ++f)
                af[f] = *(const bf16x8*)(At + (wm * (BM / 2) + f * 16 + fr) * 64 + kk + kg);
#pragma unroll
            for (int f = 0; f < NF; ++f)
                bfr[f] = *(const bf16x8*)(Bt + (wn * (BN / 2) + f * 16 + fr) * 64 + kk + kg);
#pragma unroll
            for (int mf = 0; mf < MF; ++mf)
#pragma unroll
                for (int nf = 0; nf < NF; ++nf)
                    acc[mf][nf] = MFMA16(af[mf], bfr[nf], acc[mf][nf]);
        }
        __syncthreads();
    }
    const int rb = (lane >> 4) << 2;
#pragma unroll
    for (int mf = 0; mf < MF; ++mf)
#pragma unroll
        for (int nf = 0; nf < NF; ++nf) {
            int n = n0 + wn * (BN / 2) + nf * 16 + fr;
            float bn = 0.f;
            if constexpr (OUTF32) bn = bias[n];
#pragma unroll
            for (int r = 0; r < 4; ++r) {
                int mm = m0 + wm * (BM / 2) + mf * 16 + rb + r;
                float v = acc[mf][nf][r];
                if constexpr (OUTF32)
                    Yf[(size_t)mm * ldy + n] = v + bn;
                else
                    Yb[(size_t)mm * ldy + n] = (bf16)(v * oscale);
            }
        }
}

// fp32 -> bf16 conversion pass (x inputs optional). 16M elems max, 4/thread.
__global__ __launch_bounds__(256) void cvt_all(const float* q, const float* k, const float* v,
                                               const float* Wq, const float* Wk,
                                               const float* Wv, const float* Wo,
                                               bf16* qc, bf16* kc, bf16* vc,
                                               bf16* Wqc, bf16* Wkc, bf16* Wvc, bf16* Woc,
                                               int doX) {
    const size_t NX = (size_t)Bsz * T * E;  // 4M
    const size_t NW = (size_t)E * E;        // 1M
    const size_t xtot = doX ? 3 * NX : 0;
    const size_t nwork = (xtot + 4 * NW) >> 2;
    for (size_t t = (size_t)blockIdx.x * 256 + threadIdx.x; t < nwork;
         t += (size_t)gridDim.x * 256) {
        size_t i = t << 2;
        const float* s;
        bf16* d;
        size_t off;
        if (i < xtot) {
            size_t w = i / NX;
            off = i - w * NX;
            s = w == 0 ? q : (w == 1 ? k : v);
            d = w == 0 ? qc : (w == 1 ? kc : vc);
        } else {
            size_t j = i - xtot;
            size_t w = j / NW;
            off = j - w * NW;
            s = w == 0 ? Wq : (w == 1 ? Wk : (w == 2 ? Wv : Wo));
            d = w == 0 ? Wqc : (w == 1 ? Wkc : (w == 2 ? Wvc : Woc));
        }
        const float4 x = *(const float4*)(s + off);
        bf16x4 y = {(bf16)x.x, (bf16)x.y, (bf16)x.z, (bf16)x.w};
        *(bf16x4*)(d + off) = y;
    }
}

// Fused Q/K/V^T projections: 768 blocks, XCD-swizzled, no dead blocks.
template <bool XB16, bool WB16>
__global__ __launch_bounds__(256) void qkv_proj(
    const float* q32, const float* k32, const float* v32,
    const bf16* q16, const bf16* k16, const bf16* v16,
    const float* Wq32, const float* Wk32, const float* Wv32,
    const bf16* Wq16, const bf16* Wk16, const bf16* Wv16,
    bf16* Qb, bf16* Kb, bf16* Vt) {
    __shared__ bf16 At[128 * 64];
    __shared__ bf16 Bt[128 * 64];
    const int bid = blockIdx.x;
    const int wid = (bid & 7) * 96 + (bid >> 3);  // 768 % 8 == 0: bijective
    if (wid < 512) {
        int s = wid >> 8;  // 0=Q (scaled by QSCALE), 1=K
        int t = wid & 255;
        int m0 = (t >> 3) * 128, n0 = (t & 7) * 128;
        gemm_body<XB16, WB16, 4, 4, false>(At, Bt,
                                           s ? k16 : q16, s ? k32 : q32,
                                           s ? Wk16 : Wq16, s ? Wk32 : Wq32,
                                           s ? Kb : Qb, nullptr, nullptr, m0, n0, E, E,
                                           s ? 1.0f : QSCALE);
    } else {
        int r = wid - 512;
        int b = r >> 7, rr = r & 127;
        int m0 = (rr >> 4) * 128, n0 = (rr & 15) * 128;
        gemm_body<WB16, XB16, 4, 4, false>(At, Bt,
                                           Wv16, Wv32,
                                           v16 + (size_t)b * T * E, v32 + (size_t)b * T * E,
                                           Vt + (size_t)b * E * T, nullptr, nullptr,
                                           m0, n0, E, T, 1.0f);
    }
}

// Output projection: 64x128 tiles -> 512 blocks (2/CU), fp32 out + bias.
template <bool WB16>
__global__ __launch_bounds__(256) void out_proj(const bf16* Xb, const bf16* W16,
                                                const float* W32, float* Y,
                                                const float* bias) {
    __shared__ bf16 At[64 * 64];
    __shared__ bf16 Bt[128 * 64];
    const int bid = blockIdx.x;
    const int wid = (bid & 7) * 64 + (bid >> 3);  // 512 % 8 == 0: bijective
    const int m0 = (wid >> 3) * 64, n0 = (wid & 7) * 128;
    gemm_body<true, WB16, 2, 4, true>(At, Bt, Xb, nullptr, W16, W32, nullptr, Y, bias,
                                      m0, n0, E, E, 1.0f);
}

// ---------------- Attention: flash, shared LDS-staged K/V tiles ------------
__device__ __forceinline__ uint pkbf(float a, float b) {
    uint16_t x = __builtin_bit_cast(uint16_t, (bf16)a);
    uint16_t y = __builtin_bit_cast(uint16_t, (bf16)b);
    return (uint)x | ((uint)y << 16);
}

// Q-block 128 rows (4 waves x 32 q). 64-key K/V tiles shared by all waves,
// staged via global_load_lds into XOR-swizzled LDS (pre-swizzled global src,
// m173), double-buffered with counted vmcnt + raw s_barrier (T3/T4): the
// next tile's 4 loads stay in flight across the barrier.
__global__ __launch_bounds__(256) void attn_fwd(const bf16* __restrict__ Q,
                                                const bf16* __restrict__ K,
                                                const bf16* __restrict__ Vt,
                                                bf16* __restrict__ O) {
    __shared__ __align__(16) bf16 Kl[2][64 * 64];  // [key][d], 128B rows, swizzled
    __shared__ __align__(16) bf16 Vl[2][64 * 64];  // [d][key], 128B rows, swizzled

    // Paired mapping: blocks g and g+256 carry (qb, 15-qb) of the SAME head ->
    // complementary work on (typically) the same CU + shared K/V in L2.
    const int g = blockIdx.x;
    const int lo = g & 255;
    const int xcd = lo & 7, jj = lo >> 3;      // jj 0..31
    const int hb = xcd * 4 + (jj & 3);         // 4 head-batches per XCD
    const int qhi = 15 - (jj >> 2);            // 8..15
    const int qb = (g < 256) ? qhi : 15 - qhi; // heavy half first
    const int h = hb & 15, b = hb >> 4;

    const int tid = threadIdx.x, lane = tid & 63, w = tid >> 6;
    const int l31 = lane & 31, hi = lane >> 5;
    const int q0 = qb * 128 + w * 32;  // this wave's 32 q-rows

    const bf16* Qp = Q + (size_t)b * T * E + h * Dh;
    const bf16* Kp = K + (size_t)b * T * E + h * Dh;
    const bf16* Vp = Vt + ((size_t)b * E + h * Dh) * T;

    // staging lane geometry: linear LDS dest + pre-swizzled global source
    const int rsub = lane >> 3;            // row within 8-row slab
    const int csw = (lane & 7) ^ rsub;     // swizzled 16B-chunk index
    const int swz = (l31 & 7);             // read-side XOR

    bf16x8 qf[4];
#pragma unroll
    for (int t = 0; t < 4; ++t)
        qf[t] = *(const bf16x8*)(Qp + (size_t)(q0 + l31) * E + t * 16 + hi * 8);

    f32x16 o0 = {}, o1 = {};
    float m = -1e30f, l = 0.f;
    const int myDiag = 4 * qb + w;
    const int nK2 = 2 * qb + 2;  // 64-key tiles needed

    // prologue: stage tile 0 into buf 0 (4 gll16 per wave: 2 K + 2 V slabs)
#pragma unroll
    for (int ii = 0; ii < 2; ++ii)
        gll16(Kp + (size_t)(16 * w + 8 * ii + rsub) * E + csw * 8, &Kl[0][(2 * w + ii) * 512]);
#pragma unroll
    for (int ii = 0; ii < 2; ++ii)
        gll16(Vp + (size_t)(16 * w + 8 * ii + rsub) * T + csw * 8, &Vl[0][(2 * w + ii) * 512]);

    int cur = 0;
#pragma unroll 1
    for (int K2 = 0; K2 < nK2; ++K2) {
        if (K2 + 1 < nK2) {
            const int kb = (K2 + 1) * 64;
            const bf16* Kg = Kp + (size_t)kb * E;
            const bf16* Vg = Vp + kb;
            bf16* dK = &Kl[cur ^ 1][0];
            bf16* dV = &Vl[cur ^ 1][0];
#pragma unroll
            for (int ii = 0; ii < 2; ++ii)
                gll16(Kg + (size_t)(16 * w + 8 * ii + rsub) * E + csw * 8, dK + (2 * w + ii) * 512);
#pragma unroll
            for (int ii = 0; ii < 2; ++ii)
                gll16(Vg + (size_t)(16 * w + 8 * ii + rsub) * T + csw * 8, dV + (2 * w + ii) * 512);
            asm volatile("s_waitcnt vmcnt(4)" ::: "memory");  // cur-tile landed; next in flight
        } else {
            asm volatile("s_waitcnt vmcnt(0)" ::: "memory");
        }
        __builtin_amdgcn_s_barrier();
        asm volatile("" ::: "memory");

        const bf16* KL = &Kl[cur][0];
        const bf16* VL = &Vl[cur][0];
#pragma unroll
        for (int s = 0; s < 2; ++s) {
            const int ktsub = 2 * K2 + s;
            if (ktsub <= myDiag) {  // wave-uniform branch
                const bool dg = (ktsub == myDiag);
                bf16x8 kf[4];
#pragma unroll
                for (int t = 0; t < 4; ++t)
                    kf[t] = *(const bf16x8*)(KL + (s * 32 + l31) * 64 +
                                             ((((t << 1) | hi) ^ swz) << 3));
                __builtin_amdgcn_s_setprio(1);
                f32x16 sa = {};
#pragma unroll
                for (int t = 0; t < 4; ++t) sa = MFMA32(kf[t], qf[t], sa);
                __builtin_amdgcn_s_setprio(0);

                if (dg) {
#pragma unroll
                    for (int r = 0; r < 16; ++r) {
                        int key = (r & 3) + 8 * (r >> 2) + 4 * hi;
                        if (key > l31) sa[r] = -1e30f;
                    }
                }
                // row-max: tree + cross-half
                float t8[8];
#pragma unroll
                for (int r = 0; r < 8; ++r) t8[r] = fmaxf(sa[r], sa[r + 8]);
#pragma unroll
                for (int r = 0; r < 4; ++r) t8[r] = fmaxf(t8[r], t8[r + 4]);
                float pm = fmaxf(fmaxf(t8[0], t8[1]), fmaxf(t8[2], t8[3]));
                pm = fmaxf(pm, __shfl_xor(pm, 32, 64));

                if (!__all(pm - m <= 11.5f)) {  // deferred rescale (T13)
                    float mn = fmaxf(m, pm);
                    float al = exp2fast(m - mn);
                    m = mn;
                    l *= al;
#pragma unroll
                    for (int r = 0; r < 16; ++r) {
                        int qr = (r & 3) + 8 * (r >> 2) + 4 * hi;
                        float aq = __shfl(al, qr, 64);
                        o0[r] *= aq;
                        o1[r] *= aq;
                    }
                }
                float p[16];
#pragma unroll
                for (int r = 0; r < 16; ++r) p[r] = exp2fast(sa[r] - m);
                float u8[8];
#pragma unroll
                for (int r = 0; r < 8; ++r) u8[r] = p[r] + p[r + 8];
#pragma unroll
                for (int r = 0; r < 4; ++r) u8[r] = u8[r] + u8[r + 4];
                float ps = (u8[0] + u8[1]) + (u8[2] + u8[3]);
                l += ps + __shfl_xor(ps, 32, 64);

                bf16x8 vf[2][2];
#pragma unroll
                for (int db = 0; db < 2; ++db)
#pragma unroll
                    for (int cc = 0; cc < 2; ++cc)
                        vf[db][cc] = *(const bf16x8*)(VL + (db * 32 + l31) * 64 +
                                                      ((((s << 2) | (cc << 1) | hi) ^ swz) << 3));
                // P -> PV A-fragments (round-4 verified shfl_xor routing)
                __builtin_amdgcn_s_setprio(1);
#pragma unroll
                for (int cc = 0; cc < 2; ++cc) {
                    int bse = cc * 8;
                    uint x0 = pkbf(p[bse + 0], p[bse + 1]);
                    uint x1 = pkbf(p[bse + 2], p[bse + 3]);
                    uint y0 = pkbf(p[bse + 4], p[bse + 5]);
                    uint y1 = pkbf(p[bse + 6], p[bse + 7]);
                    uint sx0 = __shfl_xor(x0, 32, 64), sx1 = __shfl_xor(x1, 32, 64);
                    uint sy0 = __shfl_xor(y0, 32, 64), sy1 = __shfl_xor(y1, 32, 64);
                    u32x4 wv;
                    wv.x = hi ? sy0 : x0;
                    wv.y = hi ? sy1 : x1;
                    wv.z = hi ? y0 : sx0;
                    wv.w = hi ? y1 : sx1;
                    bf16x8 pa = __builtin_bit_cast(bf16x8, wv);
                    o0 = MFMA32(pa, vf[0][cc], o0);
                    o1 = MFMA32(pa, vf[1][cc], o1);
                }
                __builtin_amdgcn_s_setprio(0);
            }
        }
        asm volatile("" ::: "memory");
        __builtin_amdgcn_s_barrier();  // all waves done reading buf[cur]
        cur ^= 1;
    }

    // epilogue: direct store (each wave owns its 32 q-rows)
    bf16* Op = O + (size_t)b * T * E + h * Dh;
#pragma unroll
    for (int r = 0; r < 16; ++r) {
        int qr = (r & 3) + 8 * (r >> 2) + 4 * hi;
        float lq = __shfl(l, qr, 64);
        float inv = 1.0f / lq;
        Op[(size_t)(q0 + qr) * E + l31] = (bf16)(o0[r] * inv);
        Op[(size_t)(q0 + qr) * E + 32 + l31] = (bf16)(o1[r] * inv);
    }
}

extern "C" void kernel_launch(void* const* d_in, const int* in_sizes, int n_in,
                              void* d_out, int out_size, void* d_ws, size_t ws_size,
                              hipStream_t stream) {
    const float* k_in = (const float*)d_in[0];
    const float* q_in = (const float*)d_in[1];
    const float* v_in = (const float*)d_in[2];
    const float* Wk = (const float*)d_in[3];
    const float* Wq = (const float*)d_in[4];
    const float* Wv = (const float*)d_in[5];
    const float* Wo = (const float*)d_in[6];
    const float* bo = (const float*)d_in[7];
    float* out = (float*)d_out;

    const size_t NE = (size_t)Bsz * T * E;  // 4M
    const size_t NW = (size_t)E * E;        // 1M
    bf16* ws = (bf16*)d_ws;
    bf16* Qb = ws;            // [B*T][E]  (pre-scaled by QSCALE)
    bf16* Kb = ws + NE;       // [B*T][E]
    bf16* Vt = ws + 2 * NE;   // [B][E][T]  (pre-transposed V)
    bf16* Ab = ws + 3 * NE;   // attn out; also aliases qc (dead by then)
    bf16* Wqc = ws + 4 * NE;
    bf16* Wkc = Wqc + NW;
    bf16* Wvc = Wkc + NW;
    bf16* Woc = Wvc + NW;
    bf16* qc = Ab;            // alias: qc dead after qkv_proj, Ab written after
    bf16* kc = ws + 4 * NE + 4 * NW;
    bf16* vc = kc + NE;

    const bool planA = ws_size >= (4 * NE + 4 * NW + 2 * NE) * sizeof(bf16);  // 56 MB
    const bool planB = ws_size >= (4 * NE + 4 * NW) * sizeof(bf16);           // 40 MB

    if (planA) {
        cvt_all<<<2048, 256, 0, stream>>>(q_in, k_in, v_in, Wq, Wk, Wv, Wo,
                                          qc, kc, vc, Wqc, Wkc, Wvc, Woc, 1);
        qkv_proj<true, true><<<768, 256, 0, stream>>>(
            nullptr, nullptr, nullptr, qc, kc, vc,
            nullptr, nullptr, nullptr, Wqc, Wkc, Wvc, Qb, Kb, Vt);
    } else if (planB) {
        cvt_all<<<2048, 256, 0, stream>>>(q_in, k_in, v_in, Wq, Wk, Wv, Wo,
                                          nullptr, nullptr, nullptr, Wqc, Wkc, Wvc, Woc, 0);
        qkv_proj<false, true><<<768, 256, 0, stream>>>(
            q_in, k_in, v_in, nullptr, nullptr, nullptr,
            nullptr, nullptr, nullptr, Wqc, Wkc, Wvc, Qb, Kb, Vt);
    } else {
        qkv_proj<false, false><<<768, 256, 0, stream>>>(
            q_in, k_in, v_in, nullptr, nullptr, nullptr,
            Wq, Wk, Wv, nullptr, nullptr, nullptr, Qb, Kb, Vt);
    }

    attn_fwd<<<dim3(512), 256, 0, stream>>>(Qb, Kb, Vt, Ab);

    if (planB)
        out_proj<true><<<512, 256, 0, stream>>>(Ab, Woc, nullptr, out, bo);
    else
        out_proj<false><<<512, 256, 0, stream>>>(Ab, nullptr, Wo, out, bo);
}

// Round 11
// 143.932 us; speedup vs baseline: 2.1450x; 1.0844x over previous
//
#include <hip/hip_runtime.h>
#include <stdint.h>

typedef __bf16 bf16;
typedef bf16 bf16x8 __attribute__((ext_vector_type(8)));
typedef bf16 bf16x4 __attribute__((ext_vector_type(4)));
typedef float f32x4 __attribute__((ext_vector_type(4)));
typedef float f32x16 __attribute__((ext_vector_type(16)));
typedef unsigned int uint;
typedef uint u32x4 __attribute__((ext_vector_type(4)));

#define MFMA16(a, b, c) __builtin_amdgcn_mfma_f32_16x16x32_bf16(a, b, c, 0, 0, 0)
#define MFMA32(a, b, c) __builtin_amdgcn_mfma_f32_32x32x16_bf16(a, b, c, 0, 0, 0)

static constexpr int Bsz = 2, T = 2048, E = 1024, H = 16, Dh = 64;
// softmax scale folded into Q at projection; exp2-domain: 1/sqrt(64) * log2(e)
static constexpr float QSCALE = 0.125f * 1.44269504088896f;

__device__ __forceinline__ float exp2fast(float x) {
#if __has_builtin(__builtin_amdgcn_exp2f)
    return __builtin_amdgcn_exp2f(x);
#else
    return exp2f(x);
#endif
}

// async global->LDS, 16B per lane. LDS dest must be wave-uniform base (HW adds lane*16).
__device__ __forceinline__ void gll16(const bf16* g, bf16* l) {
    __builtin_amdgcn_global_load_lds((const __attribute__((address_space(1))) uint*)g,
                                     (__attribute__((address_space(3))) uint*)l, 16, 0, 0);
}

// ---- staging: ROWS x 64 bf16 tile into linear LDS ([row][64], 128B rows) ----
template <int ROWS>
__device__ __forceinline__ void stage_b16(bf16* lds, const bf16* g, int ldg, int wave, int lane) {
#pragma unroll
    for (int i = 0; i < ROWS / 32; ++i) {
        const int row = wave * (ROWS / 4) + i * 8;  // wave-uniform
        gll16(g + (size_t)(row + (lane >> 3)) * ldg + (lane & 7) * 8, lds + row * 64);
    }
}
template <int ROWS>
__device__ __forceinline__ void stage_f32(bf16* lds, const float* g, int ldg, int tid) {
#pragma unroll
    for (int i = 0; i < ROWS / 16; ++i) {
        int gg = tid + i * 256;
        int row = gg >> 4, c4 = (gg & 15) << 2;
        const float4 v = *(const float4*)(g + (size_t)row * ldg + c4);
        bf16x4 bv = {(bf16)v.x, (bf16)v.y, (bf16)v.z, (bf16)v.w};
        *(bf16x4*)(lds + row * 64 + c4) = bv;
    }
}

// ------------- GEMM body: Y[M,N] = A[M,K] @ B[N,K]^T (+bias) ---------------
template <bool AB16, bool BB16, int MF, int NF, bool OUTF32>
__device__ __forceinline__ void gemm_body(bf16* At, bf16* Bt,
                                          const bf16* A16, const float* A32,
                                          const bf16* B16, const float* B32,
                                          bf16* Yb, float* Yf, const float* bias,
                                          int m0, int n0, int K, int ldy, float oscale) {
    constexpr int BM = MF * 32, BN = NF * 32;
    const int tid = threadIdx.x, lane = tid & 63, wave = tid >> 6;
    const int wm = wave >> 1, wn = wave & 1;
    const int fr = lane & 15, kg = (lane >> 4) << 3;

    f32x4 acc[MF][NF] = {};

    for (int k0 = 0; k0 < K; k0 += 64) {
        if constexpr (AB16)
            stage_b16<BM>(At, A16 + (size_t)m0 * K + k0, K, wave, lane);
        else
            stage_f32<BM>(At, A32 + (size_t)m0 * K + k0, K, tid);
        if constexpr (BB16)
            stage_b16<BN>(Bt, B16 + (size_t)n0 * K + k0, K, wave, lane);
        else
            stage_f32<BN>(Bt, B32 + (size_t)n0 * K + k0, K, tid);
        __syncthreads();  // compiler drains vmcnt(0) for global_load_lds here
#pragma unroll
        for (int kk = 0; kk < 64; kk += 32) {
            bf16x8 af[MF], bfr[NF];
#pragma unroll
            for (int f = 0; f < MF; ++f)
                af[f] = *(const bf16x8*)(At + (wm * (BM / 2) + f * 16 + fr) * 64 + kk + kg);
#pragma unroll
            for (int f = 0; f < NF; ++f)
                bfr[f] = *(const bf16x8*)(Bt + (wn * (BN / 2) + f * 16 + fr) * 64 + kk + kg);
#pragma unroll
            for (int mf = 0; mf < MF; ++mf)
#pragma unroll
                for (int nf = 0; nf < NF; ++nf)
                    acc[mf][nf] = MFMA16(af[mf], bfr[nf], acc[mf][nf]);
        }
        __syncthreads();
    }
    const int rb = (lane >> 4) << 2;
#pragma unroll
    for (int mf = 0; mf < MF; ++mf)
#pragma unroll
        for (int nf = 0; nf < NF; ++nf) {
            int n = n0 + wn * (BN / 2) + nf * 16 + fr;
            float bn = 0.f;
            if constexpr (OUTF32) bn = bias[n];
#pragma unroll
            for (int r = 0; r < 4; ++r) {
                int mm = m0 + wm * (BM / 2) + mf * 16 + rb + r;
                float v = acc[mf][nf][r];
                if constexpr (OUTF32)
                    Yf[(size_t)mm * ldy + n] = v + bn;
                else
                    Yb[(size_t)mm * ldy + n] = (bf16)(v * oscale);
            }
        }
}

// fp32 -> bf16 conversion pass (x inputs optional). 16M elems max, 4/thread.
__global__ __launch_bounds__(256) void cvt_all(const float* q, const float* k, const float* v,
                                               const float* Wq, const float* Wk,
                                               const float* Wv, const float* Wo,
                                               bf16* qc, bf16* kc, bf16* vc,
                                               bf16* Wqc, bf16* Wkc, bf16* Wvc, bf16* Woc,
                                               int doX) {
    const size_t NX = (size_t)Bsz * T * E;  // 4M
    const size_t NW = (size_t)E * E;        // 1M
    const size_t xtot = doX ? 3 * NX : 0;
    const size_t nwork = (xtot + 4 * NW) >> 2;
    for (size_t t = (size_t)blockIdx.x * 256 + threadIdx.x; t < nwork;
         t += (size_t)gridDim.x * 256) {
        size_t i = t << 2;
        const float* s;
        bf16* d;
        size_t off;
        if (i < xtot) {
            size_t w = i / NX;
            off = i - w * NX;
            s = w == 0 ? q : (w == 1 ? k : v);
            d = w == 0 ? qc : (w == 1 ? kc : vc);
        } else {
            size_t j = i - xtot;
            size_t w = j / NW;
            off = j - w * NW;
            s = w == 0 ? Wq : (w == 1 ? Wk : (w == 2 ? Wv : Wo));
            d = w == 0 ? Wqc : (w == 1 ? Wkc : (w == 2 ? Wvc : Woc));
        }
        const float4 x = *(const float4*)(s + off);
        bf16x4 y = {(bf16)x.x, (bf16)x.y, (bf16)x.z, (bf16)x.w};
        *(bf16x4*)(d + off) = y;
    }
}

// Fused Q/K/V^T projections: 768 blocks, XCD-swizzled, no dead blocks.
template <bool XB16, bool WB16>
__global__ __launch_bounds__(256) void qkv_proj(
    const float* q32, const float* k32, const float* v32,
    const bf16* q16, const bf16* k16, const bf16* v16,
    const float* Wq32, const float* Wk32, const float* Wv32,
    const bf16* Wq16, const bf16* Wk16, const bf16* Wv16,
    bf16* Qb, bf16* Kb, bf16* Vt) {
    __shared__ bf16 At[128 * 64];
    __shared__ bf16 Bt[128 * 64];
    const int bid = blockIdx.x;
    const int wid = (bid & 7) * 96 + (bid >> 3);  // 768 % 8 == 0: bijective
    if (wid < 512) {
        int s = wid >> 8;  // 0=Q (scaled by QSCALE), 1=K
        int t = wid & 255;
        int m0 = (t >> 3) * 128, n0 = (t & 7) * 128;
        gemm_body<XB16, WB16, 4, 4, false>(At, Bt,
                                           s ? k16 : q16, s ? k32 : q32,
                                           s ? Wk16 : Wq16, s ? Wk32 : Wq32,
                                           s ? Kb : Qb, nullptr, nullptr, m0, n0, E, E,
                                           s ? 1.0f : QSCALE);
    } else {
        int r = wid - 512;
        int b = r >> 7, rr = r & 127;
        int m0 = (rr >> 4) * 128, n0 = (rr & 15) * 128;
        gemm_body<WB16, XB16, 4, 4, false>(At, Bt,
                                           Wv16, Wv32,
                                           v16 + (size_t)b * T * E, v32 + (size_t)b * T * E,
                                           Vt + (size_t)b * E * T, nullptr, nullptr,
                                           m0, n0, E, T, 1.0f);
    }
}

// Output projection: 64x128 tiles -> 512 blocks (2/CU), fp32 out + bias.
template <bool WB16>
__global__ __launch_bounds__(256) void out_proj(const bf16* Xb, const bf16* W16,
                                                const float* W32, float* Y,
                                                const float* bias) {
    __shared__ bf16 At[64 * 64];
    __shared__ bf16 Bt[128 * 64];
    const int bid = blockIdx.x;
    const int wid = (bid & 7) * 64 + (bid >> 3);  // 512 % 8 == 0: bijective
    const int m0 = (wid >> 3) * 64, n0 = (wid & 7) * 128;
    gemm_body<true, WB16, 2, 4, true>(At, Bt, Xb, nullptr, W16, W32, nullptr, Y, bias,
                                      m0, n0, E, E, 1.0f);
}

// ---------------- Attention: flash, shared LDS-staged K/V tiles ------------
__device__ __forceinline__ uint pkbf(float a, float b) {
    uint16_t x = __builtin_bit_cast(uint16_t, (bf16)a);
    uint16_t y = __builtin_bit_cast(uint16_t, (bf16)b);
    return (uint)x | ((uint)y << 16);
}

// One flat 64-key tile. DMODE: 0 = interior (no mask), 1 = diagonal with q in
// upper half (s1 diag-masked), 2 = diagonal with q in lower half (s0
// diag-masked, keys 32-63 entirely dead -> skipped).
// Two independent QK chains (s0,s1); ONE softmax pass over all 32 scores.
template <int DMODE>
__device__ __forceinline__ void attn_tile64(const bf16* KL, const bf16* VL,
                                            int l31, int hi, int swz,
                                            const bf16x8 (&qf)[4],
                                            f32x16& o0, f32x16& o1, float& m, float& l) {
    constexpr int NCC = (DMODE == 2) ? 2 : 4;
    f32x16 s0 = {}, s1 = {};
    {
        bf16x8 kf[4];
#pragma unroll
        for (int t = 0; t < 4; ++t)
            kf[t] = *(const bf16x8*)(KL + l31 * 64 + ((((t << 1) | hi) ^ swz) << 3));
        __builtin_amdgcn_s_setprio(1);
#pragma unroll
        for (int t = 0; t < 4; ++t) s0 = MFMA32(kf[t], qf[t], s0);
        __builtin_amdgcn_s_setprio(0);
    }
    if constexpr (DMODE != 2) {
        bf16x8 kf[4];
#pragma unroll
        for (int t = 0; t < 4; ++t)
            kf[t] = *(const bf16x8*)(KL + (32 + l31) * 64 + ((((t << 1) | hi) ^ swz) << 3));
        __builtin_amdgcn_s_setprio(1);
#pragma unroll
        for (int t = 0; t < 4; ++t) s1 = MFMA32(kf[t], qf[t], s1);
        __builtin_amdgcn_s_setprio(0);
    }
    // V fragments preloaded here: ds_read latency hides under softmax VALU
    bf16x8 vfa[NCC], vfb[NCC];
#pragma unroll
    for (int cc = 0; cc < NCC; ++cc) {
        vfa[cc] = *(const bf16x8*)(VL + l31 * 64 + ((((cc << 1) | hi) ^ swz) << 3));
        vfb[cc] = *(const bf16x8*)(VL + (32 + l31) * 64 + ((((cc << 1) | hi) ^ swz) << 3));
    }
    // causal mask (diagonal tiles only)
    if constexpr (DMODE == 2) {
#pragma unroll
        for (int r = 0; r < 16; ++r) {
            int key = (r & 3) + 8 * (r >> 2) + 4 * hi;
            if (key > l31) s0[r] = -1e30f;
        }
    }
    if constexpr (DMODE == 1) {
#pragma unroll
        for (int r = 0; r < 16; ++r) {
            int key = (r & 3) + 8 * (r >> 2) + 4 * hi;
            if (key > l31) s1[r] = -1e30f;
        }
    }
    // single row-max tree over all live scores
    float t8[8];
    if constexpr (DMODE == 2) {
#pragma unroll
        for (int r = 0; r < 8; ++r) t8[r] = fmaxf(s0[r], s0[r + 8]);
    } else {
#pragma unroll
        for (int r = 0; r < 8; ++r)
            t8[r] = fmaxf(fmaxf(s0[r], s0[r + 8]), fmaxf(s1[r], s1[r + 8]));
    }
#pragma unroll
    for (int r = 0; r < 4; ++r) t8[r] = fmaxf(t8[r], t8[r + 4]);
    float pm = fmaxf(fmaxf(t8[0], t8[1]), fmaxf(t8[2], t8[3]));
    pm = fmaxf(pm, __shfl_xor(pm, 32, 64));

    if (!__all(pm - m <= 11.5f)) {  // deferred rescale (T13), 8*log2e
        float mn = fmaxf(m, pm);
        float al = exp2fast(m - mn);
        m = mn;
        l *= al;
#pragma unroll
        for (int r = 0; r < 16; ++r) {
            int qr = (r & 3) + 8 * (r >> 2) + 4 * hi;
            float aq = __shfl(al, qr, 64);
            o0[r] *= aq;
            o1[r] *= aq;
        }
    }
    // exp in place (masked entries -> 0), single sum tree
#pragma unroll
    for (int r = 0; r < 16; ++r) s0[r] = exp2fast(s0[r] - m);
    if constexpr (DMODE != 2) {
#pragma unroll
        for (int r = 0; r < 16; ++r) s1[r] = exp2fast(s1[r] - m);
    }
    float u8[8];
    if constexpr (DMODE == 2) {
#pragma unroll
        for (int r = 0; r < 8; ++r) u8[r] = s0[r] + s0[r + 8];
    } else {
#pragma unroll
        for (int r = 0; r < 8; ++r) u8[r] = (s0[r] + s0[r + 8]) + (s1[r] + s1[r + 8]);
    }
#pragma unroll
    for (int r = 0; r < 4; ++r) u8[r] = u8[r] + u8[r + 4];
    float ps = (u8[0] + u8[1]) + (u8[2] + u8[3]);
    l += ps + __shfl_xor(ps, 32, 64);

    // pack + PV (round-4 verified shfl_xor routing, per 16-key fragment)
    __builtin_amdgcn_s_setprio(1);
#pragma unroll
    for (int cc = 0; cc < NCC; ++cc) {
        const f32x16& ph = (cc < 2) ? s0 : s1;  // static after unroll
        const int bse = (cc & 1) * 8;
        uint x0 = pkbf(ph[bse + 0], ph[bse + 1]);
        uint x1 = pkbf(ph[bse + 2], ph[bse + 3]);
        uint y0 = pkbf(ph[bse + 4], ph[bse + 5]);
        uint y1 = pkbf(ph[bse + 6], ph[bse + 7]);
        uint sx0 = __shfl_xor(x0, 32, 64), sx1 = __shfl_xor(x1, 32, 64);
        uint sy0 = __shfl_xor(y0, 32, 64), sy1 = __shfl_xor(y1, 32, 64);
        u32x4 wv;
        wv.x = hi ? sy0 : x0;
        wv.y = hi ? sy1 : x1;
        wv.z = hi ? y0 : sx0;
        wv.w = hi ? y1 : sx1;
        bf16x8 pa = __builtin_bit_cast(bf16x8, wv);
        o0 = MFMA32(pa, vfa[cc], o0);
        o1 = MFMA32(pa, vfb[cc], o1);
    }
    __builtin_amdgcn_s_setprio(0);
}

// Q-block 128 rows (4 waves x 32 q). 64-key K/V tiles shared by all waves,
// staged via global_load_lds into XOR-swizzled LDS (pre-swizzled global src),
// double-buffered with counted vmcnt + raw s_barrier.
__global__ __launch_bounds__(256) void attn_fwd(const bf16* __restrict__ Q,
                                                const bf16* __restrict__ K,
                                                const bf16* __restrict__ Vt,
                                                bf16* __restrict__ O) {
    __shared__ __align__(16) bf16 Kl[2][64 * 64];  // [key][d], 128B rows, swizzled
    __shared__ __align__(16) bf16 Vl[2][64 * 64];  // [d][key], 128B rows, swizzled

    const int g = blockIdx.x;
    const int lo = g & 255;
    const int xcd = lo & 7, jj = lo >> 3;       // jj 0..31
    const int hb = xcd * 4 + (jj & 3);          // 4 head-batches per XCD
    const int qhi = 15 - (jj >> 2);             // 8..15
    const int qb = (g < 256) ? qhi : 15 - qhi;  // heavy half first
    const int h = hb & 15, b = hb >> 4;

    const int tid = threadIdx.x, lane = tid & 63, w = tid >> 6;
    const int l31 = lane & 31, hi = lane >> 5;
    const int q0 = qb * 128 + w * 32;  // this wave's 32 q-rows

    const bf16* Qp = Q + (size_t)b * T * E + h * Dh;
    const bf16* Kp = K + (size_t)b * T * E + h * Dh;
    const bf16* Vp = Vt + ((size_t)b * E + h * Dh) * T;

    // staging lane geometry: linear LDS dest + pre-swizzled global source
    const int rsub = lane >> 3;         // row within 8-row slab
    const int csw = (lane & 7) ^ rsub;  // swizzled 16B-chunk index
    const int swz = (l31 & 7);          // read-side XOR

    bf16x8 qf[4];
#pragma unroll
    for (int t = 0; t < 4; ++t)
        qf[t] = *(const bf16x8*)(Qp + (size_t)(q0 + l31) * E + t * 16 + hi * 8);

    f32x16 o0 = {}, o1 = {};
    float m = -1e30f, l = 0.f;
    const int ktD = 2 * qb + (w >> 1);  // this wave's diagonal 64-tile
    const int nK2 = 2 * qb + 2;         // 64-key tiles staged by the block

    // prologue: stage tile 0 into buf 0 (4 gll16 per wave: 2 K + 2 V slabs)
#pragma unroll
    for (int ii = 0; ii < 2; ++ii)
        gll16(Kp + (size_t)(16 * w + 8 * ii + rsub) * E + csw * 8, &Kl[0][(2 * w + ii) * 512]);
#pragma unroll
    for (int ii = 0; ii < 2; ++ii)
        gll16(Vp + (size_t)(16 * w + 8 * ii + rsub) * T + csw * 8, &Vl[0][(2 * w + ii) * 512]);

    int cur = 0;
#pragma unroll 1
    for (int K2 = 0; K2 < nK2; ++K2) {
        if (K2 + 1 < nK2) {
            const int kb = (K2 + 1) * 64;
            const bf16* Kg = Kp + (size_t)kb * E;
            const bf16* Vg = Vp + kb;
            bf16* dK = &Kl[cur ^ 1][0];
            bf16* dV = &Vl[cur ^ 1][0];
#pragma unroll
            for (int ii = 0; ii < 2; ++ii)
                gll16(Kg + (size_t)(16 * w + 8 * ii + rsub) * E + csw * 8, dK + (2 * w + ii) * 512);
#pragma unroll
            for (int ii = 0; ii < 2; ++ii)
                gll16(Vg + (size_t)(16 * w + 8 * ii + rsub) * T + csw * 8, dV + (2 * w + ii) * 512);
            asm volatile("s_waitcnt vmcnt(4)" ::: "memory");  // cur-tile landed; next in flight
        } else {
            asm volatile("s_waitcnt vmcnt(0)" ::: "memory");
        }
        __builtin_amdgcn_s_barrier();
        asm volatile("" ::: "memory");

        const bf16* KL = &Kl[cur][0];
        const bf16* VL = &Vl[cur][0];
        if (K2 < ktD) {
            attn_tile64<0>(KL, VL, l31, hi, swz, qf, o0, o1, m, l);
        } else if (K2 == ktD) {
            if (w & 1)
                attn_tile64<1>(KL, VL, l31, hi, swz, qf, o0, o1, m, l);
            else
                attn_tile64<2>(KL, VL, l31, hi, swz, qf, o0, o1, m, l);
        }
        asm volatile("" ::: "memory");
        __builtin_amdgcn_s_barrier();  // all waves done reading buf[cur]
        cur ^= 1;
    }

    // epilogue: direct store (each wave owns its 32 q-rows)
    bf16* Op = O + (size_t)b * T * E + h * Dh;
#pragma unroll
    for (int r = 0; r < 16; ++r) {
        int qr = (r & 3) + 8 * (r >> 2) + 4 * hi;
        float lq = __shfl(l, qr, 64);
        float inv = 1.0f / lq;
        Op[(size_t)(q0 + qr) * E + l31] = (bf16)(o0[r] * inv);
        Op[(size_t)(q0 + qr) * E + 32 + l31] = (bf16)(o1[r] * inv);
    }
}

extern "C" void kernel_launch(void* const* d_in, const int* in_sizes, int n_in,
                              void* d_out, int out_size, void* d_ws, size_t ws_size,
                              hipStream_t stream) {
    const float* k_in = (const float*)d_in[0];
    const float* q_in = (const float*)d_in[1];
    const float* v_in = (const float*)d_in[2];
    const float* Wk = (const float*)d_in[3];
    const float* Wq = (const float*)d_in[4];
    const float* Wv = (const float*)d_in[5];
    const float* Wo = (const float*)d_in[6];
    const float* bo = (const float*)d_in[7];
    float* out = (float*)d_out;

    const size_t NE = (size_t)Bsz * T * E;  // 4M
    const size_t NW = (size_t)E * E;        // 1M
    bf16* ws = (bf16*)d_ws;
    bf16* Qb = ws;            // [B*T][E]  (pre-scaled by QSCALE)
    bf16* Kb = ws + NE;       // [B*T][E]
    bf16* Vt = ws + 2 * NE;   // [B][E][T]  (pre-transposed V)
    bf16* Ab = ws + 3 * NE;   // attn out; also aliases qc (dead by then)
    bf16* Wqc = ws + 4 * NE;
    bf16* Wkc = Wqc + NW;
    bf16* Wvc = Wkc + NW;
    bf16* Woc = Wvc + NW;
    bf16* qc = Ab;            // alias: qc dead after qkv_proj, Ab written after
    bf16* kc = ws + 4 * NE + 4 * NW;
    bf16* vc = kc + NE;

    const bool planA = ws_size >= (4 * NE + 4 * NW + 2 * NE) * sizeof(bf16);  // 56 MB
    const bool planB = ws_size >= (4 * NE + 4 * NW) * sizeof(bf16);           // 40 MB

    if (planA) {
        cvt_all<<<2048, 256, 0, stream>>>(q_in, k_in, v_in, Wq, Wk, Wv, Wo,
                                          qc, kc, vc, Wqc, Wkc, Wvc, Woc, 1);
        qkv_proj<true, true><<<768, 256, 0, stream>>>(
            nullptr, nullptr, nullptr, qc, kc, vc,
            nullptr, nullptr, nullptr, Wqc, Wkc, Wvc, Qb, Kb, Vt);
    } else if (planB) {
        cvt_all<<<2048, 256, 0, stream>>>(q_in, k_in, v_in, Wq, Wk, Wv, Wo,
                                          nullptr, nullptr, nullptr, Wqc, Wkc, Wvc, Woc, 0);
        qkv_proj<false, true><<<768, 256, 0, stream>>>(
            q_in, k_in, v_in, nullptr, nullptr, nullptr,
            nullptr, nullptr, nullptr, Wqc, Wkc, Wvc, Qb, Kb, Vt);
    } else {
        qkv_proj<false, false><<<768, 256, 0, stream>>>(
            q_in, k_in, v_in, nullptr, nullptr, nullptr,
            Wq, Wk, Wv, nullptr, nullptr, nullptr, Qb, Kb, Vt);
    }

    attn_fwd<<<dim3(512), 256, 0, stream>>>(Qb, Kb, Vt, Ab);

    if (planB)
        out_proj<true><<<512, 256, 0, stream>>>(Ab, Woc, nullptr, out, bo);
    else
        out_proj<false><<<512, 256, 0, stream>>>(Ab, nullptr, Wo, out, bo);
}